// Round 2
// 4916.428 us; speedup vs baseline: 2.4482x; 2.4482x over previous
//
#include <hip/hip_runtime.h>
#include <hip/hip_fp16.h>

// TriangleMultiplicationOutgoing — MI355X (gfx950)
// ROUND 6: resubmit of round-5 (MFMA fp16 pass1) with two crash-vector fixes:
//   (a) wq (fp16 weights, 128 KB) now lives in d_out, NOT appended past the
//       128 MB a_t|b_t region of ws (possible ws overrun -> container abort).
//       Ordering: pass0 writes wq into d_out; pass1 reads it; pass2 fully
//       overwrites d_out; pass3 rewrites in place. Same-stream serialized.
//   (b) explicit 16-byte alignment on LDS arrays read via ds_read_b128.
// pass2/pass3 remain the verified round-4 scalar builds.

typedef unsigned short u16;
typedef unsigned int u32;
typedef unsigned short u16x8 __attribute__((ext_vector_type(8)));
typedef _Float16 f16;
typedef _Float16 f16x8 __attribute__((ext_vector_type(8)));
typedef _Float16 f16x2 __attribute__((ext_vector_type(2)));
typedef float f32x4 __attribute__((ext_vector_type(4)));

#define NROW 262144  // 512*512 spatial positions
#define CH 128

__device__ __forceinline__ float sigmoidf_(float x) {
  return 1.0f / (1.0f + __expf(-x));
}

// ---------------- pass 0: weights fp32 -> fp16, order [pa, ga, pb, gb] ------
__global__ __launch_bounds__(256) void k_pass0(
    const float* __restrict__ wpa, const float* __restrict__ wga,
    const float* __restrict__ wpb, const float* __restrict__ wgb,
    f16* __restrict__ wq) {
  const int m = blockIdx.x >> 6;                       // 64 blocks per matrix
  const int idx = ((blockIdx.x & 63) << 8) + threadIdx.x;
  const float* src = (m == 0) ? wpa : (m == 1) ? wga : (m == 2) ? wpb : wgb;
  wq[(size_t)m * CH * CH + idx] = (f16)src[idx];
}

// ---------------- pass 1: LN(z) + 4 projections -> a,b (fp16, [c][r]) -------
// 64 rows per block (4096 blocks, 256 threads = 4 waves).
// Wave w computes output columns [w*32, w*32+32) for all 4 weight matrices.
__global__ __launch_bounds__(256) void k_pass1(
    const float* __restrict__ z, const float* __restrict__ pm,
    const float* __restrict__ lnw, const float* __restrict__ lnb,
    const f16* __restrict__ wq,
    f16* __restrict__ a_t, f16* __restrict__ b_t) {
  __shared__ __attribute__((aligned(16))) f16 zn[64 * CH];      // 16 KB
  __shared__ __attribute__((aligned(16))) f16 ab[2 * CH * 64];  // 32 KB
  __shared__ float pmv[64];
  const int t = threadIdx.x, lane = t & 63, w = t >> 6;
  const size_t r0 = (size_t)blockIdx.x * 64;
  const int c0 = lane * 2;
  const float lw0 = lnw[c0], lw1 = lnw[c0 + 1];
  const float lb0 = lnb[c0], lb1 = lnb[c0 + 1];

  // Phase A: LayerNorm, 16 rows per wave, fp32 shuffle-reduce, fp16 to LDS.
  for (int i = 0; i < 16; i++) {
    const int row = w * 16 + i;
    const float2 v = *(const float2*)(z + (r0 + row) * CH + c0);
    float s = v.x + v.y, sq = v.x * v.x + v.y * v.y;
#pragma unroll
    for (int off = 32; off > 0; off >>= 1) {
      s += __shfl_xor(s, off);
      sq += __shfl_xor(sq, off);
    }
    const float mu = s * (1.0f / 128.0f);
    const float rs = rsqrtf(sq * (1.0f / 128.0f) - mu * mu + 1e-5f);
    f16x2 p;
    p.x = (f16)((v.x - mu) * rs * lw0 + lb0);
    p.y = (f16)((v.y - mu) * rs * lw1 + lb1);
    // swizzle both write and read sides with the same involution (rule 21)
    const int byte = (row * 256 + c0 * 2) ^ ((row & 7) << 4);
    *(f16x2*)((char*)zn + byte) = p;
    if (lane == 0) pmv[row] = pm[r0 + row];
  }
  __syncthreads();

  // Phase B: MFMA GEMM. D[row][col] layout: col=lane&15, row=(lane>>4)*4+reg.
  const int g = lane >> 4, ln16 = lane & 15;
#pragma unroll
  for (int pair = 0; pair < 2; pair++) {  // 0:(pa,ga)->a  1:(pb,gb)->b
    const f16* __restrict__ wp = wq + (size_t)(pair * 2 + 0) * CH * CH;
    const f16* __restrict__ wg = wq + (size_t)(pair * 2 + 1) * CH * CH;
#pragma unroll
    for (int mt = 0; mt < 4; mt++) {
      const int m0 = mt * 16;
      f16x8 af[4];
#pragma unroll
      for (int ks = 0; ks < 4; ks++) {
        const int row = m0 + ln16;
        const int byte = (row * 256 + (ks * 32 + g * 8) * 2) ^ ((row & 7) << 4);
        af[ks] = *(const f16x8*)((const char*)zn + byte);
      }
#pragma unroll
      for (int f = 0; f < 2; f++) {
        const int col = w * 32 + f * 16 + ln16;  // output channel
        f32x4 accP = {0.f, 0.f, 0.f, 0.f}, accG = {0.f, 0.f, 0.f, 0.f};
#pragma unroll
        for (int ks = 0; ks < 4; ks++) {
          const size_t wo = (size_t)col * CH + ks * 32 + g * 8;
          const f16x8 bp = *(const f16x8*)(wp + wo);
          const f16x8 bg = *(const f16x8*)(wg + wo);
          accP = __builtin_amdgcn_mfma_f32_16x16x32_f16(af[ks], bp, accP, 0, 0, 0);
          accG = __builtin_amdgcn_mfma_f32_16x16x32_f16(af[ks], bg, accG, 0, 0, 0);
        }
        // epilogue: rows m0+g*4..+3, mask * sigmoid(gate) * proj -> fp16
        uint2 pk;
        {
          const int rbase = m0 + g * 4;
          const float v0 = pmv[rbase + 0] * sigmoidf_(accG[0]) * accP[0];
          const float v1 = pmv[rbase + 1] * sigmoidf_(accG[1]) * accP[1];
          const float v2 = pmv[rbase + 2] * sigmoidf_(accG[2]) * accP[2];
          const float v3 = pmv[rbase + 3] * sigmoidf_(accG[3]) * accP[3];
          f16x2 h01, h23;
          h01.x = (f16)v0; h01.y = (f16)v1;
          h23.x = (f16)v2; h23.y = (f16)v3;
          pk.x = *(u32*)&h01;
          pk.y = *(u32*)&h23;
        }
        const int byte = pair * (CH * 64 * 2) +
                         (((col * 64 + m0 + g * 4) * 2) ^ ((col & 7) << 4));
        *(uint2*)((char*)ab + byte) = pk;  // 8B, 2-way bank alias (free)
      }
    }
  }
  __syncthreads();

  // Phase C: coalesced writeout. Thread t -> channel o = t>>1, rows h*32..+31.
  // 64 B contiguous per thread into a_t/b_t [c][r] layout.
  const int o = t >> 1, h = t & 1;
#pragma unroll
  for (int sel = 0; sel < 2; sel++) {
    f16* __restrict__ dst = (sel ? b_t : a_t) + (size_t)o * NROW + r0 + h * 32;
#pragma unroll
    for (int e = 0; e < 4; e++) {
      const int byte = sel * (CH * 64 * 2) +
                       (((o * 64 + h * 32 + e * 8) * 2) ^ ((o & 7) << 4));
      *(uint4*)(dst + e * 8) = *(const uint4*)((const char*)ab + byte);
    }
  }
}

// ------- pass 2: o[i,j,c] = sum_k a[i,k,c]*b[j,k,c]  (scalar fp32 tiled) ----
// UNCHANGED from verified round-4 build.
__global__ __launch_bounds__(256) void k_pass2(
    const __half* __restrict__ a_t, const __half* __restrict__ b_t,
    float* __restrict__ o_rc) {
  __shared__ u16 Ah[128][33];  // +1 pad breaks stride conflicts
  __shared__ u16 Bh[128][33];
  const int t = threadIdx.x;
  const int bx = blockIdx.x;
  const int c = bx >> 4, tl = bx & 15;
  const int i0 = (tl >> 2) * 128, j0 = (tl & 3) * 128;
  const u16* __restrict__ Ab = (const u16*)a_t + (size_t)c * NROW + (size_t)i0 * 512;
  const u16* __restrict__ Bb = (const u16*)b_t + (size_t)c * NROW + (size_t)j0 * 512;
  const int ig = t >> 4, jg = t & 15;  // 16x16 thread grid, 8x8 each

  float acc[8][8];
#pragma unroll
  for (int u = 0; u < 8; u++)
#pragma unroll
    for (int vv = 0; vv < 8; vv++) acc[u][vv] = 0.f;

  for (int k0 = 0; k0 < 512; k0 += 32) {
#pragma unroll
    for (int vld = 0; vld < 2; vld++) {
      const int idx = t * 2 + vld;  // 0..511
      const int row = idx >> 2, k8 = (idx & 3) * 8;
      const u16x8 va = *(const u16x8*)(Ab + (size_t)row * 512 + k0 + k8);
      const u16x8 vb = *(const u16x8*)(Bb + (size_t)row * 512 + k0 + k8);
#pragma unroll
      for (int e = 0; e < 8; e++) {
        Ah[row][k8 + e] = va[e];
        Bh[row][k8 + e] = vb[e];
      }
    }
    __syncthreads();
    for (int k = 0; k < 32; k++) {
      float av[8], bv[8];
#pragma unroll
      for (int u = 0; u < 8; u++)
        av[u] = __half2float(*(const __half*)&Ah[ig * 8 + u][k]);
#pragma unroll
      for (int vv = 0; vv < 8; vv++)
        bv[vv] = __half2float(*(const __half*)&Bh[jg * 8 + vv][k]);
#pragma unroll
      for (int u = 0; u < 8; u++)
#pragma unroll
        for (int vv = 0; vv < 8; vv++) acc[u][vv] += av[u] * bv[vv];
    }
    __syncthreads();
  }

#pragma unroll
  for (int u = 0; u < 8; u++)
#pragma unroll
    for (int vv = 0; vv < 8; vv++) {
      const int i = i0 + ig * 8 + u, j = j0 + jg * 8 + vv;
      o_rc[(size_t)(i * 512 + j) * CH + c] = acc[u][vv];
    }
}

// ------- pass 3: out = sigmoid(zn@w_g^T) * (LN(o) @ w_o^T)  (scalar fp32) ---
// UNCHANGED from verified round-4 build.
__global__ __launch_bounds__(256) void k_pass3(
    const float* __restrict__ z,
    const float* __restrict__ lnwi, const float* __restrict__ lnbi,
    const float* __restrict__ lnwo, const float* __restrict__ lnbo,
    const float* __restrict__ wg, const float* __restrict__ wo,
    float* __restrict__ out) {
  __shared__ float on[4][CH];
  __shared__ float zn[4][CH];
  const int t = threadIdx.x, lane = t & 63, w = t >> 6;
  const int r = blockIdx.x * 4 + w;
  const int c0 = lane * 2;

  {
    const float2 ov = *(const float2*)(out + (size_t)r * CH + c0);
    float s = ov.x + ov.y, sq = ov.x * ov.x + ov.y * ov.y;
#pragma unroll
    for (int off = 32; off > 0; off >>= 1) {
      s += __shfl_xor(s, off);
      sq += __shfl_xor(sq, off);
    }
    const float mu = s * (1.0f / 128.0f);
    const float rs = rsqrtf(sq * (1.0f / 128.0f) - mu * mu + 1e-5f);
    on[w][c0] = (ov.x - mu) * rs * lnwo[c0] + lnbo[c0];
    on[w][c0 + 1] = (ov.y - mu) * rs * lnwo[c0 + 1] + lnbo[c0 + 1];
  }
  {
    const float2 zv = *(const float2*)(z + (size_t)r * CH + c0);
    float s = zv.x + zv.y, sq = zv.x * zv.x + zv.y * zv.y;
#pragma unroll
    for (int off = 32; off > 0; off >>= 1) {
      s += __shfl_xor(s, off);
      sq += __shfl_xor(sq, off);
    }
    const float mu = s * (1.0f / 128.0f);
    const float rs = rsqrtf(sq * (1.0f / 128.0f) - mu * mu + 1e-5f);
    zn[w][c0] = (zv.x - mu) * rs * lnwi[c0] + lnbi[c0];
    zn[w][c0 + 1] = (zv.y - mu) * rs * lnwi[c0 + 1] + lnbi[c0 + 1];
  }
  __syncthreads();

#pragma unroll
  for (int half = 0; half < 2; half++) {
    const int o = c0 + half;
    float dg = 0.f, dp = 0.f;
    for (int c = 0; c < CH; c++) {
      dg += wg[o * CH + c] * zn[w][c];
      dp += wo[o * CH + c] * on[w][c];
    }
    out[(size_t)r * CH + o] = sigmoidf_(dg) * dp;
  }
}

extern "C" void kernel_launch(void* const* d_in, const int* in_sizes, int n_in,
                              void* d_out, int out_size, void* d_ws, size_t ws_size,
                              hipStream_t stream) {
  const float* z = (const float*)d_in[0];
  const float* pm = (const float*)d_in[1];
  const float* ln_in_w = (const float*)d_in[2];
  const float* ln_in_b = (const float*)d_in[3];
  const float* ln_out_w = (const float*)d_in[4];
  const float* ln_out_b = (const float*)d_in[5];
  const float* w_pa = (const float*)d_in[6];
  const float* w_pb = (const float*)d_in[7];
  const float* w_ga = (const float*)d_in[8];
  const float* w_gb = (const float*)d_in[9];
  const float* w_g = (const float*)d_in[10];
  const float* w_o = (const float*)d_in[11];

  // ws: a_t | b_t (fp16, 64 MB each) = exactly 128 MB.
  // wq (fp16 weights, 128 KB) lives at the START of d_out: written by pass0,
  // read by pass1, then d_out is fully overwritten by pass2 (same stream).
  f16* a_t = (f16*)d_ws;
  f16* b_t = a_t + (size_t)CH * NROW;
  float* out = (float*)d_out;
  f16* wq = (f16*)d_out;

  k_pass0<<<256, 256, 0, stream>>>(w_pa, w_ga, w_pb, w_gb, wq);
  k_pass1<<<4096, 256, 0, stream>>>(z, pm, ln_in_w, ln_in_b, wq, a_t, b_t);
  k_pass2<<<2048, 256, 0, stream>>>((const __half*)a_t, (const __half*)b_t, out);
  k_pass3<<<65536, 256, 0, stream>>>(z, ln_in_w, ln_in_b, ln_out_w, ln_out_b,
                                     w_g, w_o, out);
}

// Round 3
// 1396.292 us; speedup vs baseline: 8.6202x; 3.5211x over previous
//
#include <hip/hip_runtime.h>
#include <hip/hip_fp16.h>

// TriangleMultiplicationOutgoing — MI355X (gfx950)
// ROUND 7: pass3 rewritten as MFMA fp16 GEMM (same recipe as pass1's round-6
// rewrite, which verified). pass1/pass2 untouched.
//   - k_cvt2: w_g,w_o fp32->fp16 into START of ws (a_t region, dead after
//     pass2; stream-serialized) — no extra ws, stays at exactly 128 MB.
//   - k_pass3: 64 rows/block. LN(z)->zn, LN(o)->on (fp16 swizzled LDS),
//     mfma_f32_16x16x32_f16 gate+proj GEMMs, fused sigmoid epilogue,
//     fp32 result staged in swizzled LDS, coalesced 128B/thread stores.
//   - In-place safe: o rows fully read (phase A) before overwritten (phase D),
//     __syncthreads between; blocks own disjoint rows.

typedef unsigned short u16;
typedef unsigned int u32;
typedef unsigned short u16x8 __attribute__((ext_vector_type(8)));
typedef _Float16 f16;
typedef _Float16 f16x8 __attribute__((ext_vector_type(8)));
typedef _Float16 f16x2 __attribute__((ext_vector_type(2)));
typedef float f32x4 __attribute__((ext_vector_type(4)));

#define NROW 262144  // 512*512 spatial positions
#define CH 128

__device__ __forceinline__ float sigmoidf_(float x) {
  return 1.0f / (1.0f + __expf(-x));
}

// ---------------- pass 0: weights fp32 -> fp16, order [pa, ga, pb, gb] ------
__global__ __launch_bounds__(256) void k_pass0(
    const float* __restrict__ wpa, const float* __restrict__ wga,
    const float* __restrict__ wpb, const float* __restrict__ wgb,
    f16* __restrict__ wq) {
  const int m = blockIdx.x >> 6;                       // 64 blocks per matrix
  const int idx = ((blockIdx.x & 63) << 8) + threadIdx.x;
  const float* src = (m == 0) ? wpa : (m == 1) ? wga : (m == 2) ? wpb : wgb;
  wq[(size_t)m * CH * CH + idx] = (f16)src[idx];
}

// ---------------- cvt2: w_g, w_o fp32 -> fp16 (into ws head) ----------------
__global__ __launch_bounds__(256) void k_cvt2(
    const float* __restrict__ w_g, const float* __restrict__ w_o,
    f16* __restrict__ wq3) {
  const int m = blockIdx.x >> 6;                       // 64 blocks per matrix
  const int idx = ((blockIdx.x & 63) << 8) + threadIdx.x;
  const float* src = (m == 0) ? w_g : w_o;
  wq3[(size_t)m * CH * CH + idx] = (f16)src[idx];
}

// ---------------- pass 1: LN(z) + 4 projections -> a,b (fp16, [c][r]) -------
// UNCHANGED from verified round-6 build.
__global__ __launch_bounds__(256) void k_pass1(
    const float* __restrict__ z, const float* __restrict__ pm,
    const float* __restrict__ lnw, const float* __restrict__ lnb,
    const f16* __restrict__ wq,
    f16* __restrict__ a_t, f16* __restrict__ b_t) {
  __shared__ __attribute__((aligned(16))) f16 zn[64 * CH];      // 16 KB
  __shared__ __attribute__((aligned(16))) f16 ab[2 * CH * 64];  // 32 KB
  __shared__ float pmv[64];
  const int t = threadIdx.x, lane = t & 63, w = t >> 6;
  const size_t r0 = (size_t)blockIdx.x * 64;
  const int c0 = lane * 2;
  const float lw0 = lnw[c0], lw1 = lnw[c0 + 1];
  const float lb0 = lnb[c0], lb1 = lnb[c0 + 1];

  for (int i = 0; i < 16; i++) {
    const int row = w * 16 + i;
    const float2 v = *(const float2*)(z + (r0 + row) * CH + c0);
    float s = v.x + v.y, sq = v.x * v.x + v.y * v.y;
#pragma unroll
    for (int off = 32; off > 0; off >>= 1) {
      s += __shfl_xor(s, off);
      sq += __shfl_xor(sq, off);
    }
    const float mu = s * (1.0f / 128.0f);
    const float rs = rsqrtf(sq * (1.0f / 128.0f) - mu * mu + 1e-5f);
    f16x2 p;
    p.x = (f16)((v.x - mu) * rs * lw0 + lb0);
    p.y = (f16)((v.y - mu) * rs * lw1 + lb1);
    const int byte = (row * 256 + c0 * 2) ^ ((row & 7) << 4);
    *(f16x2*)((char*)zn + byte) = p;
    if (lane == 0) pmv[row] = pm[r0 + row];
  }
  __syncthreads();

  const int g = lane >> 4, ln16 = lane & 15;
#pragma unroll
  for (int pair = 0; pair < 2; pair++) {  // 0:(pa,ga)->a  1:(pb,gb)->b
    const f16* __restrict__ wp = wq + (size_t)(pair * 2 + 0) * CH * CH;
    const f16* __restrict__ wg = wq + (size_t)(pair * 2 + 1) * CH * CH;
#pragma unroll
    for (int mt = 0; mt < 4; mt++) {
      const int m0 = mt * 16;
      f16x8 af[4];
#pragma unroll
      for (int ks = 0; ks < 4; ks++) {
        const int row = m0 + ln16;
        const int byte = (row * 256 + (ks * 32 + g * 8) * 2) ^ ((row & 7) << 4);
        af[ks] = *(const f16x8*)((const char*)zn + byte);
      }
#pragma unroll
      for (int f = 0; f < 2; f++) {
        const int col = w * 32 + f * 16 + ln16;  // output channel
        f32x4 accP = {0.f, 0.f, 0.f, 0.f}, accG = {0.f, 0.f, 0.f, 0.f};
#pragma unroll
        for (int ks = 0; ks < 4; ks++) {
          const size_t wo = (size_t)col * CH + ks * 32 + g * 8;
          const f16x8 bp = *(const f16x8*)(wp + wo);
          const f16x8 bg = *(const f16x8*)(wg + wo);
          accP = __builtin_amdgcn_mfma_f32_16x16x32_f16(af[ks], bp, accP, 0, 0, 0);
          accG = __builtin_amdgcn_mfma_f32_16x16x32_f16(af[ks], bg, accG, 0, 0, 0);
        }
        uint2 pk;
        {
          const int rbase = m0 + g * 4;
          const float v0 = pmv[rbase + 0] * sigmoidf_(accG[0]) * accP[0];
          const float v1 = pmv[rbase + 1] * sigmoidf_(accG[1]) * accP[1];
          const float v2 = pmv[rbase + 2] * sigmoidf_(accG[2]) * accP[2];
          const float v3 = pmv[rbase + 3] * sigmoidf_(accG[3]) * accP[3];
          f16x2 h01, h23;
          h01.x = (f16)v0; h01.y = (f16)v1;
          h23.x = (f16)v2; h23.y = (f16)v3;
          pk.x = *(u32*)&h01;
          pk.y = *(u32*)&h23;
        }
        const int byte = pair * (CH * 64 * 2) +
                         (((col * 64 + m0 + g * 4) * 2) ^ ((col & 7) << 4));
        *(uint2*)((char*)ab + byte) = pk;
      }
    }
  }
  __syncthreads();

  const int o = t >> 1, h = t & 1;
#pragma unroll
  for (int sel = 0; sel < 2; sel++) {
    f16* __restrict__ dst = (sel ? b_t : a_t) + (size_t)o * NROW + r0 + h * 32;
#pragma unroll
    for (int e = 0; e < 4; e++) {
      const int byte = sel * (CH * 64 * 2) +
                       (((o * 64 + h * 32 + e * 8) * 2) ^ ((o & 7) << 4));
      *(uint4*)(dst + e * 8) = *(const uint4*)((const char*)ab + byte);
    }
  }
}

// ------- pass 2: o[i,j,c] = sum_k a[i,k,c]*b[j,k,c]  (scalar fp32 tiled) ----
// UNCHANGED from verified round-4 build.
__global__ __launch_bounds__(256) void k_pass2(
    const __half* __restrict__ a_t, const __half* __restrict__ b_t,
    float* __restrict__ o_rc) {
  __shared__ u16 Ah[128][33];  // +1 pad breaks stride conflicts
  __shared__ u16 Bh[128][33];
  const int t = threadIdx.x;
  const int bx = blockIdx.x;
  const int c = bx >> 4, tl = bx & 15;
  const int i0 = (tl >> 2) * 128, j0 = (tl & 3) * 128;
  const u16* __restrict__ Ab = (const u16*)a_t + (size_t)c * NROW + (size_t)i0 * 512;
  const u16* __restrict__ Bb = (const u16*)b_t + (size_t)c * NROW + (size_t)j0 * 512;
  const int ig = t >> 4, jg = t & 15;  // 16x16 thread grid, 8x8 each

  float acc[8][8];
#pragma unroll
  for (int u = 0; u < 8; u++)
#pragma unroll
    for (int vv = 0; vv < 8; vv++) acc[u][vv] = 0.f;

  for (int k0 = 0; k0 < 512; k0 += 32) {
#pragma unroll
    for (int vld = 0; vld < 2; vld++) {
      const int idx = t * 2 + vld;  // 0..511
      const int row = idx >> 2, k8 = (idx & 3) * 8;
      const u16x8 va = *(const u16x8*)(Ab + (size_t)row * 512 + k0 + k8);
      const u16x8 vb = *(const u16x8*)(Bb + (size_t)row * 512 + k0 + k8);
#pragma unroll
      for (int e = 0; e < 8; e++) {
        Ah[row][k8 + e] = va[e];
        Bh[row][k8 + e] = vb[e];
      }
    }
    __syncthreads();
    for (int k = 0; k < 32; k++) {
      float av[8], bv[8];
#pragma unroll
      for (int u = 0; u < 8; u++)
        av[u] = __half2float(*(const __half*)&Ah[ig * 8 + u][k]);
#pragma unroll
      for (int vv = 0; vv < 8; vv++)
        bv[vv] = __half2float(*(const __half*)&Bh[jg * 8 + vv][k]);
#pragma unroll
      for (int u = 0; u < 8; u++)
#pragma unroll
        for (int vv = 0; vv < 8; vv++) acc[u][vv] += av[u] * bv[vv];
    }
    __syncthreads();
  }

#pragma unroll
  for (int u = 0; u < 8; u++)
#pragma unroll
    for (int vv = 0; vv < 8; vv++) {
      const int i = i0 + ig * 8 + u, j = j0 + jg * 8 + vv;
      o_rc[(size_t)(i * 512 + j) * CH + c] = acc[u][vv];
    }
}

// ------- pass 3: out = sigmoid(zn@w_g^T) * (LN(o) @ w_o^T)  (MFMA fp16) -----
// 64 rows/block, 4096 blocks. In-place on d_out.
__global__ __launch_bounds__(256) void k_pass3(
    const float* __restrict__ z,
    const float* __restrict__ lnwi, const float* __restrict__ lnbi,
    const float* __restrict__ lnwo, const float* __restrict__ lnbo,
    const f16* __restrict__ wq3,  // [w_g | w_o] fp16, 128x128 each
    float* __restrict__ out) {
  __shared__ __attribute__((aligned(16))) f16 zn[64 * CH];    // 16 KB
  __shared__ __attribute__((aligned(16))) f16 on[64 * CH];    // 16 KB
  __shared__ __attribute__((aligned(16))) float res[64 * CH]; // 32 KB
  const int t = threadIdx.x, lane = t & 63, w = t >> 6;
  const size_t r0 = (size_t)blockIdx.x * 64;
  const int c0 = lane * 2;
  const float lwi0 = lnwi[c0], lwi1 = lnwi[c0 + 1];
  const float lbi0 = lnbi[c0], lbi1 = lnbi[c0 + 1];
  const float lwo0 = lnwo[c0], lwo1 = lnwo[c0 + 1];
  const float lbo0 = lnbo[c0], lbo1 = lnbo[c0 + 1];

  // Phase A: LN(z) and LN(o) for 16 rows per wave, fp16 to swizzled LDS.
  for (int i = 0; i < 16; i++) {
    const int row = w * 16 + i;
    const float2 zv = *(const float2*)(z + (r0 + row) * CH + c0);
    const float2 ov = *(const float2*)(out + (r0 + row) * CH + c0);
    float s1 = zv.x + zv.y, q1 = zv.x * zv.x + zv.y * zv.y;
    float s2 = ov.x + ov.y, q2 = ov.x * ov.x + ov.y * ov.y;
#pragma unroll
    for (int off = 32; off > 0; off >>= 1) {
      s1 += __shfl_xor(s1, off);
      q1 += __shfl_xor(q1, off);
      s2 += __shfl_xor(s2, off);
      q2 += __shfl_xor(q2, off);
    }
    const float mu1 = s1 * (1.0f / 128.0f);
    const float rs1 = rsqrtf(q1 * (1.0f / 128.0f) - mu1 * mu1 + 1e-5f);
    const float mu2 = s2 * (1.0f / 128.0f);
    const float rs2 = rsqrtf(q2 * (1.0f / 128.0f) - mu2 * mu2 + 1e-5f);
    f16x2 pz, po;
    pz.x = (f16)((zv.x - mu1) * rs1 * lwi0 + lbi0);
    pz.y = (f16)((zv.y - mu1) * rs1 * lwi1 + lbi1);
    po.x = (f16)((ov.x - mu2) * rs2 * lwo0 + lbo0);
    po.y = (f16)((ov.y - mu2) * rs2 * lwo1 + lbo1);
    const int byte = (row * 256 + c0 * 2) ^ ((row & 7) << 4);
    *(f16x2*)((char*)zn + byte) = pz;
    *(f16x2*)((char*)on + byte) = po;
  }
  __syncthreads();

  // Phase B: MFMA. gate = zn @ w_g^T, proj = on @ w_o^T.
  const int g = lane >> 4, ln16 = lane & 15;
  const f16* __restrict__ wg = wq3;
  const f16* __restrict__ wo = wq3 + (size_t)CH * CH;
#pragma unroll
  for (int mt = 0; mt < 4; mt++) {
    const int m0 = mt * 16;
    f16x8 az[4], ao[4];
#pragma unroll
    for (int ks = 0; ks < 4; ks++) {
      const int row = m0 + ln16;
      const int byte = (row * 256 + (ks * 32 + g * 8) * 2) ^ ((row & 7) << 4);
      az[ks] = *(const f16x8*)((const char*)zn + byte);
      ao[ks] = *(const f16x8*)((const char*)on + byte);
    }
#pragma unroll
    for (int f = 0; f < 2; f++) {
      const int col = w * 32 + f * 16 + ln16;  // output channel
      f32x4 accG = {0.f, 0.f, 0.f, 0.f}, accP = {0.f, 0.f, 0.f, 0.f};
#pragma unroll
      for (int ks = 0; ks < 4; ks++) {
        const size_t woff = (size_t)col * CH + ks * 32 + g * 8;
        const f16x8 bg = *(const f16x8*)(wg + woff);
        const f16x8 bo = *(const f16x8*)(wo + woff);
        accG = __builtin_amdgcn_mfma_f32_16x16x32_f16(az[ks], bg, accG, 0, 0, 0);
        accP = __builtin_amdgcn_mfma_f32_16x16x32_f16(ao[ks], bo, accP, 0, 0, 0);
      }
      // D layout: col = lane&15 (-> col), rows m0+g*4+reg. Fuse epilogue,
      // stage fp32 into swizzled res tile.
#pragma unroll
      for (int reg = 0; reg < 4; reg++) {
        const int row = m0 + g * 4 + reg;
        const float v = sigmoidf_(accG[reg]) * accP[reg];
        const int byte = (row * 512 + col * 4) ^ ((row & 7) << 4);
        *(float*)((char*)res + byte) = v;
      }
    }
  }
  __syncthreads();

  // Phase C: coalesced writeout. Thread t -> row t>>2, quarter t&3 (32 floats,
  // 128 B contiguous per thread).
  const int row = t >> 2, q = t & 3;
  float* __restrict__ dst = out + (r0 + row) * CH + q * 32;
#pragma unroll
  for (int e = 0; e < 8; e++) {
    const int byte = (row * 512 + q * 128 + e * 16) ^ ((row & 7) << 4);
    *(float4*)(dst + e * 4) = *(const float4*)((const char*)res + byte);
  }
}

extern "C" void kernel_launch(void* const* d_in, const int* in_sizes, int n_in,
                              void* d_out, int out_size, void* d_ws, size_t ws_size,
                              hipStream_t stream) {
  const float* z = (const float*)d_in[0];
  const float* pm = (const float*)d_in[1];
  const float* ln_in_w = (const float*)d_in[2];
  const float* ln_in_b = (const float*)d_in[3];
  const float* ln_out_w = (const float*)d_in[4];
  const float* ln_out_b = (const float*)d_in[5];
  const float* w_pa = (const float*)d_in[6];
  const float* w_pb = (const float*)d_in[7];
  const float* w_ga = (const float*)d_in[8];
  const float* w_gb = (const float*)d_in[9];
  const float* w_g = (const float*)d_in[10];
  const float* w_o = (const float*)d_in[11];

  // ws: a_t | b_t (fp16, 64 MB each) = exactly 128 MB.
  // wq (pass1 weights fp16, 128 KB) lives at the START of d_out: written by
  // pass0, read by pass1, then d_out fully overwritten by pass2.
  // wq3 (pass3 weights fp16, 64 KB) lives at the START of ws (a_t region),
  // written by k_cvt2 AFTER pass2 has consumed a_t (same stream, serialized).
  f16* a_t = (f16*)d_ws;
  f16* b_t = a_t + (size_t)CH * NROW;
  float* out = (float*)d_out;
  f16* wq = (f16*)d_out;
  f16* wq3 = (f16*)d_ws;

  k_pass0<<<256, 256, 0, stream>>>(w_pa, w_ga, w_pb, w_gb, wq);
  k_pass1<<<4096, 256, 0, stream>>>(z, pm, ln_in_w, ln_in_b, wq, a_t, b_t);
  k_pass2<<<2048, 256, 0, stream>>>((const __half*)a_t, (const __half*)b_t, out);
  k_cvt2<<<128, 256, 0, stream>>>(w_g, w_o, wq3);
  k_pass3<<<4096, 256, 0, stream>>>(z, ln_in_w, ln_in_b, ln_out_w, ln_out_b,
                                    wq3, out);
}

// Round 4
// 1076.343 us; speedup vs baseline: 11.1826x; 1.2973x over previous
//
#include <hip/hip_runtime.h>
#include <hip/hip_fp16.h>

// TriangleMultiplicationOutgoing — MI355X (gfx950)
// ROUND 8: pass2 rewritten as MFMA fp16 batched GEMM (per-channel 512x512x512,
// O_c = A_c * B_c^T). pass1/pass3 untouched (verified rounds 6/7).
//   - block = 1 channel x 128x128 (i,j) tile; 4 waves x 64x64 quadrant.
//   - BK=64, double-buffered XOR-swizzled LDS, reg-staged T14 ordering
//     (global loads issued before MFMA cluster, ds_write after, 1 barrier/step)
//   - mfma_f32_16x16x32_f16, fp32 accum (same acc precision as scalar build).
//   - XCD-clustered remap: all 128 c-blocks of a tile run consecutively on one
//     XCD so partial 64B output lines merge in its L2 (write-amp fix).

typedef unsigned short u16;
typedef unsigned int u32;
typedef unsigned short u16x8 __attribute__((ext_vector_type(8)));
typedef _Float16 f16;
typedef _Float16 f16x8 __attribute__((ext_vector_type(8)));
typedef _Float16 f16x2 __attribute__((ext_vector_type(2)));
typedef float f32x4 __attribute__((ext_vector_type(4)));

#define NROW 262144  // 512*512 spatial positions
#define CH 128

__device__ __forceinline__ float sigmoidf_(float x) {
  return 1.0f / (1.0f + __expf(-x));
}

// ---------------- pass 0: weights fp32 -> fp16, order [pa, ga, pb, gb] ------
__global__ __launch_bounds__(256) void k_pass0(
    const float* __restrict__ wpa, const float* __restrict__ wga,
    const float* __restrict__ wpb, const float* __restrict__ wgb,
    f16* __restrict__ wq) {
  const int m = blockIdx.x >> 6;                       // 64 blocks per matrix
  const int idx = ((blockIdx.x & 63) << 8) + threadIdx.x;
  const float* src = (m == 0) ? wpa : (m == 1) ? wga : (m == 2) ? wpb : wgb;
  wq[(size_t)m * CH * CH + idx] = (f16)src[idx];
}

// ---------------- cvt2: w_g, w_o fp32 -> fp16 (into ws head) ----------------
__global__ __launch_bounds__(256) void k_cvt2(
    const float* __restrict__ w_g, const float* __restrict__ w_o,
    f16* __restrict__ wq3) {
  const int m = blockIdx.x >> 6;                       // 64 blocks per matrix
  const int idx = ((blockIdx.x & 63) << 8) + threadIdx.x;
  const float* src = (m == 0) ? w_g : w_o;
  wq3[(size_t)m * CH * CH + idx] = (f16)src[idx];
}

// ---------------- pass 1: LN(z) + 4 projections -> a,b (fp16, [c][r]) -------
// UNCHANGED from verified round-6 build.
__global__ __launch_bounds__(256) void k_pass1(
    const float* __restrict__ z, const float* __restrict__ pm,
    const float* __restrict__ lnw, const float* __restrict__ lnb,
    const f16* __restrict__ wq,
    f16* __restrict__ a_t, f16* __restrict__ b_t) {
  __shared__ __attribute__((aligned(16))) f16 zn[64 * CH];      // 16 KB
  __shared__ __attribute__((aligned(16))) f16 ab[2 * CH * 64];  // 32 KB
  __shared__ float pmv[64];
  const int t = threadIdx.x, lane = t & 63, w = t >> 6;
  const size_t r0 = (size_t)blockIdx.x * 64;
  const int c0 = lane * 2;
  const float lw0 = lnw[c0], lw1 = lnw[c0 + 1];
  const float lb0 = lnb[c0], lb1 = lnb[c0 + 1];

  for (int i = 0; i < 16; i++) {
    const int row = w * 16 + i;
    const float2 v = *(const float2*)(z + (r0 + row) * CH + c0);
    float s = v.x + v.y, sq = v.x * v.x + v.y * v.y;
#pragma unroll
    for (int off = 32; off > 0; off >>= 1) {
      s += __shfl_xor(s, off);
      sq += __shfl_xor(sq, off);
    }
    const float mu = s * (1.0f / 128.0f);
    const float rs = rsqrtf(sq * (1.0f / 128.0f) - mu * mu + 1e-5f);
    f16x2 p;
    p.x = (f16)((v.x - mu) * rs * lw0 + lb0);
    p.y = (f16)((v.y - mu) * rs * lw1 + lb1);
    const int byte = (row * 256 + c0 * 2) ^ ((row & 7) << 4);
    *(f16x2*)((char*)zn + byte) = p;
    if (lane == 0) pmv[row] = pm[r0 + row];
  }
  __syncthreads();

  const int g = lane >> 4, ln16 = lane & 15;
#pragma unroll
  for (int pair = 0; pair < 2; pair++) {  // 0:(pa,ga)->a  1:(pb,gb)->b
    const f16* __restrict__ wp = wq + (size_t)(pair * 2 + 0) * CH * CH;
    const f16* __restrict__ wg = wq + (size_t)(pair * 2 + 1) * CH * CH;
#pragma unroll
    for (int mt = 0; mt < 4; mt++) {
      const int m0 = mt * 16;
      f16x8 af[4];
#pragma unroll
      for (int ks = 0; ks < 4; ks++) {
        const int row = m0 + ln16;
        const int byte = (row * 256 + (ks * 32 + g * 8) * 2) ^ ((row & 7) << 4);
        af[ks] = *(const f16x8*)((const char*)zn + byte);
      }
#pragma unroll
      for (int f = 0; f < 2; f++) {
        const int col = w * 32 + f * 16 + ln16;  // output channel
        f32x4 accP = {0.f, 0.f, 0.f, 0.f}, accG = {0.f, 0.f, 0.f, 0.f};
#pragma unroll
        for (int ks = 0; ks < 4; ks++) {
          const size_t wo = (size_t)col * CH + ks * 32 + g * 8;
          const f16x8 bp = *(const f16x8*)(wp + wo);
          const f16x8 bg = *(const f16x8*)(wg + wo);
          accP = __builtin_amdgcn_mfma_f32_16x16x32_f16(af[ks], bp, accP, 0, 0, 0);
          accG = __builtin_amdgcn_mfma_f32_16x16x32_f16(af[ks], bg, accG, 0, 0, 0);
        }
        uint2 pk;
        {
          const int rbase = m0 + g * 4;
          const float v0 = pmv[rbase + 0] * sigmoidf_(accG[0]) * accP[0];
          const float v1 = pmv[rbase + 1] * sigmoidf_(accG[1]) * accP[1];
          const float v2 = pmv[rbase + 2] * sigmoidf_(accG[2]) * accP[2];
          const float v3 = pmv[rbase + 3] * sigmoidf_(accG[3]) * accP[3];
          f16x2 h01, h23;
          h01.x = (f16)v0; h01.y = (f16)v1;
          h23.x = (f16)v2; h23.y = (f16)v3;
          pk.x = *(u32*)&h01;
          pk.y = *(u32*)&h23;
        }
        const int byte = pair * (CH * 64 * 2) +
                         (((col * 64 + m0 + g * 4) * 2) ^ ((col & 7) << 4));
        *(uint2*)((char*)ab + byte) = pk;
      }
    }
  }
  __syncthreads();

  const int o = t >> 1, h = t & 1;
#pragma unroll
  for (int sel = 0; sel < 2; sel++) {
    f16* __restrict__ dst = (sel ? b_t : a_t) + (size_t)o * NROW + r0 + h * 32;
#pragma unroll
    for (int e = 0; e < 4; e++) {
      const int byte = sel * (CH * 64 * 2) +
                       (((o * 64 + h * 32 + e * 8) * 2) ^ ((o & 7) << 4));
      *(uint4*)(dst + e * 8) = *(const uint4*)((const char*)ab + byte);
    }
  }
}

// ------- pass 2: o[i,j,c] = sum_k a[i,k,c]*b[j,k,c]  (MFMA fp16 GEMM) -------
// Per channel c: O_c(512x512) = A_c(512x512,k-major) * B_c^T.
// Block: one c, one 128x128 (i,j) tile. 4 waves, 64x64 quadrant each.
__global__ __launch_bounds__(256) void k_pass2(
    const f16* __restrict__ a_t, const f16* __restrict__ b_t,
    float* __restrict__ o_rc) {
  __shared__ __attribute__((aligned(16))) f16 At[2][128 * 64];  // 2x16 KB
  __shared__ __attribute__((aligned(16))) f16 Bt[2][128 * 64];  // 2x16 KB
  const int t = threadIdx.x, lane = t & 63, w = t >> 6;
  // XCD-clustered remap: bx = (T&7) + 8*((T>>3)*128 + c)
  const int bx = blockIdx.x;
  const int xcd = bx & 7, s = bx >> 3;
  const int c = s & 127, T = xcd + ((s >> 7) << 3);
  const int i0 = (T >> 2) * 128, j0 = (T & 3) * 128;
  const int wr = w >> 1, wc = w & 1;          // wave quadrant
  const int g = lane >> 4, ln16 = lane & 15;

  const f16* __restrict__ Ab = a_t + (size_t)c * NROW + (size_t)i0 * 512;
  const f16* __restrict__ Bb = b_t + (size_t)c * NROW + (size_t)j0 * 512;

  // staging: thread t -> row t>>1 (0..127), half t&1 (64 B of k)
  const int srow = t >> 1, shalf = t & 1;
  const f16* __restrict__ gA = Ab + (size_t)srow * 512 + shalf * 32;
  const f16* __restrict__ gB = Bb + (size_t)srow * 512 + shalf * 32;
  int swb[4];
#pragma unroll
  for (int q = 0; q < 4; q++)
    swb[q] = srow * 128 + ((shalf * 64 + q * 16) ^ ((srow & 7) << 4));

  f32x4 acc[4][4];
#pragma unroll
  for (int mt = 0; mt < 4; mt++)
#pragma unroll
    for (int nt = 0; nt < 4; nt++) acc[mt][nt] = {0.f, 0.f, 0.f, 0.f};

  // prologue: stage K-step 0 into buf 0
  uint4 va[4], vb[4];
#pragma unroll
  for (int q = 0; q < 4; q++) {
    va[q] = *(const uint4*)(gA + q * 8);
    vb[q] = *(const uint4*)(gB + q * 8);
  }
#pragma unroll
  for (int q = 0; q < 4; q++) {
    *(uint4*)((char*)At[0] + swb[q]) = va[q];
    *(uint4*)((char*)Bt[0] + swb[q]) = vb[q];
  }
  __syncthreads();

  for (int ks = 0; ks < 8; ks++) {
    const int buf = ks & 1;
    const bool more = (ks + 1) < 8;
    if (more) {  // issue next tile's global loads early (T14)
#pragma unroll
      for (int q = 0; q < 4; q++) {
        va[q] = *(const uint4*)(gA + (ks + 1) * 64 + q * 8);
        vb[q] = *(const uint4*)(gB + (ks + 1) * 64 + q * 8);
      }
    }
    f16x8 bfr[4][2];
#pragma unroll
    for (int nt = 0; nt < 4; nt++)
#pragma unroll
      for (int kk = 0; kk < 2; kk++) {
        const int row = wc * 64 + nt * 16 + ln16;
        const int byte = row * 128 + ((kk * 64 + g * 16) ^ ((row & 7) << 4));
        bfr[nt][kk] = *(const f16x8*)((const char*)Bt[buf] + byte);
      }
#pragma unroll
    for (int mt = 0; mt < 4; mt++) {
      f16x8 afr[2];
#pragma unroll
      for (int kk = 0; kk < 2; kk++) {
        const int row = wr * 64 + mt * 16 + ln16;
        const int byte = row * 128 + ((kk * 64 + g * 16) ^ ((row & 7) << 4));
        afr[kk] = *(const f16x8*)((const char*)At[buf] + byte);
      }
#pragma unroll
      for (int nt = 0; nt < 4; nt++) {
        acc[mt][nt] =
            __builtin_amdgcn_mfma_f32_16x16x32_f16(afr[0], bfr[nt][0], acc[mt][nt], 0, 0, 0);
        acc[mt][nt] =
            __builtin_amdgcn_mfma_f32_16x16x32_f16(afr[1], bfr[nt][1], acc[mt][nt], 0, 0, 0);
      }
    }
    if (more) {  // write next tile late, after MFMA cluster
#pragma unroll
      for (int q = 0; q < 4; q++) {
        *(uint4*)((char*)At[buf ^ 1] + swb[q]) = va[q];
        *(uint4*)((char*)Bt[buf ^ 1] + swb[q]) = vb[q];
      }
    }
    __syncthreads();
  }

  // epilogue: D layout col=ln16 (->j), row=g*4+reg (->i). Scatter 4B stores;
  // XCD clustering merges the 16-channel lines in L2.
#pragma unroll
  for (int mt = 0; mt < 4; mt++)
#pragma unroll
    for (int reg = 0; reg < 4; reg++) {
      const int i = i0 + wr * 64 + mt * 16 + g * 4 + reg;
#pragma unroll
      for (int nt = 0; nt < 4; nt++) {
        const int j = j0 + wc * 64 + nt * 16 + ln16;
        o_rc[((size_t)i * 512 + j) * CH + c] = acc[mt][nt][reg];
      }
    }
}

// ------- pass 3: out = sigmoid(zn@w_g^T) * (LN(o) @ w_o^T)  (MFMA fp16) -----
// UNCHANGED from verified round-7 build.
__global__ __launch_bounds__(256) void k_pass3(
    const float* __restrict__ z,
    const float* __restrict__ lnwi, const float* __restrict__ lnbi,
    const float* __restrict__ lnwo, const float* __restrict__ lnbo,
    const f16* __restrict__ wq3,  // [w_g | w_o] fp16, 128x128 each
    float* __restrict__ out) {
  __shared__ __attribute__((aligned(16))) f16 zn[64 * CH];    // 16 KB
  __shared__ __attribute__((aligned(16))) f16 on[64 * CH];    // 16 KB
  __shared__ __attribute__((aligned(16))) float res[64 * CH]; // 32 KB
  const int t = threadIdx.x, lane = t & 63, w = t >> 6;
  const size_t r0 = (size_t)blockIdx.x * 64;
  const int c0 = lane * 2;
  const float lwi0 = lnwi[c0], lwi1 = lnwi[c0 + 1];
  const float lbi0 = lnbi[c0], lbi1 = lnbi[c0 + 1];
  const float lwo0 = lnwo[c0], lwo1 = lnwo[c0 + 1];
  const float lbo0 = lnbo[c0], lbo1 = lnbo[c0 + 1];

  for (int i = 0; i < 16; i++) {
    const int row = w * 16 + i;
    const float2 zv = *(const float2*)(z + (r0 + row) * CH + c0);
    const float2 ov = *(const float2*)(out + (r0 + row) * CH + c0);
    float s1 = zv.x + zv.y, q1 = zv.x * zv.x + zv.y * zv.y;
    float s2 = ov.x + ov.y, q2 = ov.x * ov.x + ov.y * ov.y;
#pragma unroll
    for (int off = 32; off > 0; off >>= 1) {
      s1 += __shfl_xor(s1, off);
      q1 += __shfl_xor(q1, off);
      s2 += __shfl_xor(s2, off);
      q2 += __shfl_xor(q2, off);
    }
    const float mu1 = s1 * (1.0f / 128.0f);
    const float rs1 = rsqrtf(q1 * (1.0f / 128.0f) - mu1 * mu1 + 1e-5f);
    const float mu2 = s2 * (1.0f / 128.0f);
    const float rs2 = rsqrtf(q2 * (1.0f / 128.0f) - mu2 * mu2 + 1e-5f);
    f16x2 pz, po;
    pz.x = (f16)((zv.x - mu1) * rs1 * lwi0 + lbi0);
    pz.y = (f16)((zv.y - mu1) * rs1 * lwi1 + lbi1);
    po.x = (f16)((ov.x - mu2) * rs2 * lwo0 + lbo0);
    po.y = (f16)((ov.y - mu2) * rs2 * lwo1 + lbo1);
    const int byte = (row * 256 + c0 * 2) ^ ((row & 7) << 4);
    *(f16x2*)((char*)zn + byte) = pz;
    *(f16x2*)((char*)on + byte) = po;
  }
  __syncthreads();

  const int g = lane >> 4, ln16 = lane & 15;
  const f16* __restrict__ wg = wq3;
  const f16* __restrict__ wo = wq3 + (size_t)CH * CH;
#pragma unroll
  for (int mt = 0; mt < 4; mt++) {
    const int m0 = mt * 16;
    f16x8 az[4], ao[4];
#pragma unroll
    for (int ks = 0; ks < 4; ks++) {
      const int row = m0 + ln16;
      const int byte = (row * 256 + (ks * 32 + g * 8) * 2) ^ ((row & 7) << 4);
      az[ks] = *(const f16x8*)((const char*)zn + byte);
      ao[ks] = *(const f16x8*)((const char*)on + byte);
    }
#pragma unroll
    for (int f = 0; f < 2; f++) {
      const int col = w * 32 + f * 16 + ln16;  // output channel
      f32x4 accG = {0.f, 0.f, 0.f, 0.f}, accP = {0.f, 0.f, 0.f, 0.f};
#pragma unroll
      for (int ks = 0; ks < 4; ks++) {
        const size_t woff = (size_t)col * CH + ks * 32 + g * 8;
        const f16x8 bg = *(const f16x8*)(wg + woff);
        const f16x8 bo = *(const f16x8*)(wo + woff);
        accG = __builtin_amdgcn_mfma_f32_16x16x32_f16(az[ks], bg, accG, 0, 0, 0);
        accP = __builtin_amdgcn_mfma_f32_16x16x32_f16(ao[ks], bo, accP, 0, 0, 0);
      }
#pragma unroll
      for (int reg = 0; reg < 4; reg++) {
        const int row = m0 + g * 4 + reg;
        const float v = sigmoidf_(accG[reg]) * accP[reg];
        const int byte = (row * 512 + col * 4) ^ ((row & 7) << 4);
        *(float*)((char*)res + byte) = v;
      }
    }
  }
  __syncthreads();

  const int row = t >> 2, q = t & 3;
  float* __restrict__ dst = out + (r0 + row) * CH + q * 32;
#pragma unroll
  for (int e = 0; e < 8; e++) {
    const int byte = (row * 512 + q * 128 + e * 16) ^ ((row & 7) << 4);
    *(float4*)(dst + e * 4) = *(const float4*)((const char*)res + byte);
  }
}

extern "C" void kernel_launch(void* const* d_in, const int* in_sizes, int n_in,
                              void* d_out, int out_size, void* d_ws, size_t ws_size,
                              hipStream_t stream) {
  const float* z = (const float*)d_in[0];
  const float* pm = (const float*)d_in[1];
  const float* ln_in_w = (const float*)d_in[2];
  const float* ln_in_b = (const float*)d_in[3];
  const float* ln_out_w = (const float*)d_in[4];
  const float* ln_out_b = (const float*)d_in[5];
  const float* w_pa = (const float*)d_in[6];
  const float* w_pb = (const float*)d_in[7];
  const float* w_ga = (const float*)d_in[8];
  const float* w_gb = (const float*)d_in[9];
  const float* w_g = (const float*)d_in[10];
  const float* w_o = (const float*)d_in[11];

  // ws: a_t | b_t (fp16, 64 MB each) = exactly 128 MB.
  // wq (pass1 weights fp16, 128 KB) lives at the START of d_out: written by
  // pass0, read by pass1, then d_out fully overwritten by pass2.
  // wq3 (pass3 weights fp16, 64 KB) lives at the START of ws (a_t region),
  // written by k_cvt2 AFTER pass2 has consumed a_t (same stream, serialized).
  f16* a_t = (f16*)d_ws;
  f16* b_t = a_t + (size_t)CH * NROW;
  float* out = (float*)d_out;
  f16* wq = (f16*)d_out;
  f16* wq3 = (f16*)d_ws;

  k_pass0<<<256, 256, 0, stream>>>(w_pa, w_ga, w_pb, w_gb, wq);
  k_pass1<<<4096, 256, 0, stream>>>(z, pm, ln_in_w, ln_in_b, wq, a_t, b_t);
  k_pass2<<<2048, 256, 0, stream>>>(a_t, b_t, out);
  k_cvt2<<<128, 256, 0, stream>>>(w_g, w_o, wq3);
  k_pass3<<<4096, 256, 0, stream>>>(z, ln_in_w, ln_in_b, ln_out_w, ln_out_b,
                                    wq3, out);
}

// Round 5
// 799.435 us; speedup vs baseline: 15.0560x; 1.3464x over previous
//
#include <hip/hip_runtime.h>
#include <hip/hip_fp16.h>

// TriangleMultiplicationOutgoing — MI355X (gfx950)
// ROUND 9: pass1 latency fixes (pass0/cvt2/pass2/pass3 untouched, verified).
//   - ab staging halved to 16 KB (per-pair writeout): LDS 49.6->33 KB,
//     3->4 blocks/CU.
//   - weight fragments explicitly hoisted: pair->f->{8 reg fragments}->mt
//     reuse across 4 mt tiles; 128->32 global loads/thread (VGPR +~32).
//   - LN re-shaped: 16 lanes/row x 8ch/lane, float4 loads, 4-level shuffle
//     butterfly; 4 iterations instead of 16 (3x shorter dep chain).

typedef unsigned short u16;
typedef unsigned int u32;
typedef unsigned short u16x8 __attribute__((ext_vector_type(8)));
typedef _Float16 f16;
typedef _Float16 f16x8 __attribute__((ext_vector_type(8)));
typedef _Float16 f16x2 __attribute__((ext_vector_type(2)));
typedef float f32x4 __attribute__((ext_vector_type(4)));

#define NROW 262144  // 512*512 spatial positions
#define CH 128

__device__ __forceinline__ float sigmoidf_(float x) {
  return 1.0f / (1.0f + __expf(-x));
}

// ---------------- pass 0: weights fp32 -> fp16, order [pa, ga, pb, gb] ------
__global__ __launch_bounds__(256) void k_pass0(
    const float* __restrict__ wpa, const float* __restrict__ wga,
    const float* __restrict__ wpb, const float* __restrict__ wgb,
    f16* __restrict__ wq) {
  const int m = blockIdx.x >> 6;                       // 64 blocks per matrix
  const int idx = ((blockIdx.x & 63) << 8) + threadIdx.x;
  const float* src = (m == 0) ? wpa : (m == 1) ? wga : (m == 2) ? wpb : wgb;
  wq[(size_t)m * CH * CH + idx] = (f16)src[idx];
}

// ---------------- cvt2: w_g, w_o fp32 -> fp16 (into ws head) ----------------
__global__ __launch_bounds__(256) void k_cvt2(
    const float* __restrict__ w_g, const float* __restrict__ w_o,
    f16* __restrict__ wq3) {
  const int m = blockIdx.x >> 6;                       // 64 blocks per matrix
  const int idx = ((blockIdx.x & 63) << 8) + threadIdx.x;
  const float* src = (m == 0) ? w_g : w_o;
  wq3[(size_t)m * CH * CH + idx] = (f16)src[idx];
}

// ---------------- pass 1: LN(z) + 4 projections -> a,b (fp16, [c][r]) -------
// 64 rows per block (4096 blocks, 256 threads = 4 waves).
// Wave w computes output columns [w*32, w*32+32) for all 4 weight matrices.
__global__ __launch_bounds__(256) void k_pass1(
    const float* __restrict__ z, const float* __restrict__ pm,
    const float* __restrict__ lnw, const float* __restrict__ lnb,
    const f16* __restrict__ wq,
    f16* __restrict__ a_t, f16* __restrict__ b_t) {
  __shared__ __attribute__((aligned(16))) f16 zn[64 * CH];  // 16 KB
  __shared__ __attribute__((aligned(16))) f16 ab[CH * 64];  // 16 KB (one pair)
  __shared__ float pmv[64];
  const int t = threadIdx.x, lane = t & 63, w = t >> 6;
  const size_t r0 = (size_t)blockIdx.x * 64;

  // Phase A: LayerNorm. 16 lanes per row, 8 channels per lane, 4 rows per
  // wave-iteration, 4 iterations. 4-level shuffle butterfly within 16 lanes.
  {
    const int rr = lane >> 4, q = lane & 15;
    const float4 lw0 = *(const float4*)(lnw + q * 8);
    const float4 lw1 = *(const float4*)(lnw + q * 8 + 4);
    const float4 lb0 = *(const float4*)(lnb + q * 8);
    const float4 lb1 = *(const float4*)(lnb + q * 8 + 4);
    for (int it = 0; it < 4; it++) {
      const int row = w * 16 + it * 4 + rr;
      const float* src = z + (r0 + row) * CH + q * 8;
      const float4 v0 = *(const float4*)(src);
      const float4 v1 = *(const float4*)(src + 4);
      float s = v0.x + v0.y + v0.z + v0.w + v1.x + v1.y + v1.z + v1.w;
      float sq = v0.x * v0.x + v0.y * v0.y + v0.z * v0.z + v0.w * v0.w +
                 v1.x * v1.x + v1.y * v1.y + v1.z * v1.z + v1.w * v1.w;
#pragma unroll
      for (int off = 8; off > 0; off >>= 1) {
        s += __shfl_xor(s, off);
        sq += __shfl_xor(sq, off);
      }
      const float mu = s * (1.0f / 128.0f);
      const float rs = rsqrtf(sq * (1.0f / 128.0f) - mu * mu + 1e-5f);
      f16x8 p;
      p[0] = (f16)((v0.x - mu) * rs * lw0.x + lb0.x);
      p[1] = (f16)((v0.y - mu) * rs * lw0.y + lb0.y);
      p[2] = (f16)((v0.z - mu) * rs * lw0.z + lb0.z);
      p[3] = (f16)((v0.w - mu) * rs * lw0.w + lb0.w);
      p[4] = (f16)((v1.x - mu) * rs * lw1.x + lb1.x);
      p[5] = (f16)((v1.y - mu) * rs * lw1.y + lb1.y);
      p[6] = (f16)((v1.z - mu) * rs * lw1.z + lb1.z);
      p[7] = (f16)((v1.w - mu) * rs * lw1.w + lb1.w);
      const int byte = (row * 256 + q * 16) ^ ((row & 7) << 4);
      *(f16x8*)((char*)zn + byte) = p;
      if (q == 0) pmv[row] = pm[r0 + row];
    }
  }
  __syncthreads();

  // Phase B+C: per pair — MFMA (weights hoisted per f), then writeout.
  const int g = lane >> 4, ln16 = lane & 15;
#pragma unroll
  for (int pair = 0; pair < 2; pair++) {  // 0:(pa,ga)->a  1:(pb,gb)->b
    const f16* __restrict__ wp = wq + (size_t)(pair * 2 + 0) * CH * CH;
    const f16* __restrict__ wgp = wq + (size_t)(pair * 2 + 1) * CH * CH;
#pragma unroll
    for (int f = 0; f < 2; f++) {
      const int col = w * 32 + f * 16 + ln16;  // output channel
      // hoisted weight fragments: loaded once, reused across 4 mt tiles
      f16x8 bp[4], bg[4];
#pragma unroll
      for (int ks = 0; ks < 4; ks++) {
        const size_t wo = (size_t)col * CH + ks * 32 + g * 8;
        bp[ks] = *(const f16x8*)(wp + wo);
        bg[ks] = *(const f16x8*)(wgp + wo);
      }
#pragma unroll
      for (int mt = 0; mt < 4; mt++) {
        const int m0 = mt * 16;
        const int row = m0 + ln16;
        f32x4 accP = {0.f, 0.f, 0.f, 0.f}, accG = {0.f, 0.f, 0.f, 0.f};
#pragma unroll
        for (int ks = 0; ks < 4; ks++) {
          const int byte =
              (row * 256 + (ks * 32 + g * 8) * 2) ^ ((row & 7) << 4);
          const f16x8 af = *(const f16x8*)((const char*)zn + byte);
          accP = __builtin_amdgcn_mfma_f32_16x16x32_f16(af, bp[ks], accP, 0, 0, 0);
          accG = __builtin_amdgcn_mfma_f32_16x16x32_f16(af, bg[ks], accG, 0, 0, 0);
        }
        // epilogue: rows m0+g*4..+3, mask * sigmoid(gate) * proj -> fp16
        uint2 pk;
        {
          const int rbase = m0 + g * 4;
          const float v0 = pmv[rbase + 0] * sigmoidf_(accG[0]) * accP[0];
          const float v1 = pmv[rbase + 1] * sigmoidf_(accG[1]) * accP[1];
          const float v2 = pmv[rbase + 2] * sigmoidf_(accG[2]) * accP[2];
          const float v3 = pmv[rbase + 3] * sigmoidf_(accG[3]) * accP[3];
          f16x2 h01, h23;
          h01.x = (f16)v0; h01.y = (f16)v1;
          h23.x = (f16)v2; h23.y = (f16)v3;
          pk.x = *(u32*)&h01;
          pk.y = *(u32*)&h23;
        }
        const int byte =
            ((col * 64 + m0 + g * 4) * 2) ^ ((col & 7) << 4);
        *(uint2*)((char*)ab + byte) = pk;
      }
    }
    __syncthreads();
    // Phase C: coalesced writeout of this pair. Thread t -> channel t>>1,
    // rows (t&1)*32..+31: 64 B contiguous per thread.
    {
      const int o = t >> 1, h = t & 1;
      f16* __restrict__ dst =
          (pair ? b_t : a_t) + (size_t)o * NROW + r0 + h * 32;
#pragma unroll
      for (int e = 0; e < 4; e++) {
        const int byte =
            ((o * 64 + h * 32 + e * 8) * 2) ^ ((o & 7) << 4);
        *(uint4*)(dst + e * 8) = *(const uint4*)((const char*)ab + byte);
      }
    }
    if (pair == 0) __syncthreads();  // ab reused by pair 1
  }
}

// ------- pass 2: o[i,j,c] = sum_k a[i,k,c]*b[j,k,c]  (MFMA fp16 GEMM) -------
// UNCHANGED from verified round-8 build.
__global__ __launch_bounds__(256) void k_pass2(
    const f16* __restrict__ a_t, const f16* __restrict__ b_t,
    float* __restrict__ o_rc) {
  __shared__ __attribute__((aligned(16))) f16 At[2][128 * 64];  // 2x16 KB
  __shared__ __attribute__((aligned(16))) f16 Bt[2][128 * 64];  // 2x16 KB
  const int t = threadIdx.x, lane = t & 63, w = t >> 6;
  const int bx = blockIdx.x;
  const int xcd = bx & 7, s = bx >> 3;
  const int c = s & 127, T = xcd + ((s >> 7) << 3);
  const int i0 = (T >> 2) * 128, j0 = (T & 3) * 128;
  const int wr = w >> 1, wc = w & 1;          // wave quadrant
  const int g = lane >> 4, ln16 = lane & 15;

  const f16* __restrict__ Ab = a_t + (size_t)c * NROW + (size_t)i0 * 512;
  const f16* __restrict__ Bb = b_t + (size_t)c * NROW + (size_t)j0 * 512;

  const int srow = t >> 1, shalf = t & 1;
  const f16* __restrict__ gA = Ab + (size_t)srow * 512 + shalf * 32;
  const f16* __restrict__ gB = Bb + (size_t)srow * 512 + shalf * 32;
  int swb[4];
#pragma unroll
  for (int q = 0; q < 4; q++)
    swb[q] = srow * 128 + ((shalf * 64 + q * 16) ^ ((srow & 7) << 4));

  f32x4 acc[4][4];
#pragma unroll
  for (int mt = 0; mt < 4; mt++)
#pragma unroll
    for (int nt = 0; nt < 4; nt++) acc[mt][nt] = {0.f, 0.f, 0.f, 0.f};

  uint4 va[4], vb[4];
#pragma unroll
  for (int q = 0; q < 4; q++) {
    va[q] = *(const uint4*)(gA + q * 8);
    vb[q] = *(const uint4*)(gB + q * 8);
  }
#pragma unroll
  for (int q = 0; q < 4; q++) {
    *(uint4*)((char*)At[0] + swb[q]) = va[q];
    *(uint4*)((char*)Bt[0] + swb[q]) = vb[q];
  }
  __syncthreads();

  for (int ks = 0; ks < 8; ks++) {
    const int buf = ks & 1;
    const bool more = (ks + 1) < 8;
    if (more) {
#pragma unroll
      for (int q = 0; q < 4; q++) {
        va[q] = *(const uint4*)(gA + (ks + 1) * 64 + q * 8);
        vb[q] = *(const uint4*)(gB + (ks + 1) * 64 + q * 8);
      }
    }
    f16x8 bfr[4][2];
#pragma unroll
    for (int nt = 0; nt < 4; nt++)
#pragma unroll
      for (int kk = 0; kk < 2; kk++) {
        const int row = wc * 64 + nt * 16 + ln16;
        const int byte = row * 128 + ((kk * 64 + g * 16) ^ ((row & 7) << 4));
        bfr[nt][kk] = *(const f16x8*)((const char*)Bt[buf] + byte);
      }
#pragma unroll
    for (int mt = 0; mt < 4; mt++) {
      f16x8 afr[2];
#pragma unroll
      for (int kk = 0; kk < 2; kk++) {
        const int row = wr * 64 + mt * 16 + ln16;
        const int byte = row * 128 + ((kk * 64 + g * 16) ^ ((row & 7) << 4));
        afr[kk] = *(const f16x8*)((const char*)At[buf] + byte);
      }
#pragma unroll
      for (int nt = 0; nt < 4; nt++) {
        acc[mt][nt] =
            __builtin_amdgcn_mfma_f32_16x16x32_f16(afr[0], bfr[nt][0], acc[mt][nt], 0, 0, 0);
        acc[mt][nt] =
            __builtin_amdgcn_mfma_f32_16x16x32_f16(afr[1], bfr[nt][1], acc[mt][nt], 0, 0, 0);
      }
    }
    if (more) {
#pragma unroll
      for (int q = 0; q < 4; q++) {
        *(uint4*)((char*)At[buf ^ 1] + swb[q]) = va[q];
        *(uint4*)((char*)Bt[buf ^ 1] + swb[q]) = vb[q];
      }
    }
    __syncthreads();
  }

#pragma unroll
  for (int mt = 0; mt < 4; mt++)
#pragma unroll
    for (int reg = 0; reg < 4; reg++) {
      const int i = i0 + wr * 64 + mt * 16 + g * 4 + reg;
#pragma unroll
      for (int nt = 0; nt < 4; nt++) {
        const int j = j0 + wc * 64 + nt * 16 + ln16;
        o_rc[((size_t)i * 512 + j) * CH + c] = acc[mt][nt][reg];
      }
    }
}

// ------- pass 3: out = sigmoid(zn@w_g^T) * (LN(o) @ w_o^T)  (MFMA fp16) -----
// UNCHANGED from verified round-7 build.
__global__ __launch_bounds__(256) void k_pass3(
    const float* __restrict__ z,
    const float* __restrict__ lnwi, const float* __restrict__ lnbi,
    const float* __restrict__ lnwo, const float* __restrict__ lnbo,
    const f16* __restrict__ wq3,  // [w_g | w_o] fp16, 128x128 each
    float* __restrict__ out) {
  __shared__ __attribute__((aligned(16))) f16 zn[64 * CH];    // 16 KB
  __shared__ __attribute__((aligned(16))) f16 on[64 * CH];    // 16 KB
  __shared__ __attribute__((aligned(16))) float res[64 * CH]; // 32 KB
  const int t = threadIdx.x, lane = t & 63, w = t >> 6;
  const size_t r0 = (size_t)blockIdx.x * 64;
  const int c0 = lane * 2;
  const float lwi0 = lnwi[c0], lwi1 = lnwi[c0 + 1];
  const float lbi0 = lnbi[c0], lbi1 = lnbi[c0 + 1];
  const float lwo0 = lnwo[c0], lwo1 = lnwo[c0 + 1];
  const float lbo0 = lnbo[c0], lbo1 = lnbo[c0 + 1];

  for (int i = 0; i < 16; i++) {
    const int row = w * 16 + i;
    const float2 zv = *(const float2*)(z + (r0 + row) * CH + c0);
    const float2 ov = *(const float2*)(out + (r0 + row) * CH + c0);
    float s1 = zv.x + zv.y, q1 = zv.x * zv.x + zv.y * zv.y;
    float s2 = ov.x + ov.y, q2 = ov.x * ov.x + ov.y * ov.y;
#pragma unroll
    for (int off = 32; off > 0; off >>= 1) {
      s1 += __shfl_xor(s1, off);
      q1 += __shfl_xor(q1, off);
      s2 += __shfl_xor(s2, off);
      q2 += __shfl_xor(q2, off);
    }
    const float mu1 = s1 * (1.0f / 128.0f);
    const float rs1 = rsqrtf(q1 * (1.0f / 128.0f) - mu1 * mu1 + 1e-5f);
    const float mu2 = s2 * (1.0f / 128.0f);
    const float rs2 = rsqrtf(q2 * (1.0f / 128.0f) - mu2 * mu2 + 1e-5f);
    f16x2 pz, po;
    pz.x = (f16)((zv.x - mu1) * rs1 * lwi0 + lbi0);
    pz.y = (f16)((zv.y - mu1) * rs1 * lwi1 + lbi1);
    po.x = (f16)((ov.x - mu2) * rs2 * lwo0 + lbo0);
    po.y = (f16)((ov.y - mu2) * rs2 * lwo1 + lbo1);
    const int byte = (row * 256 + c0 * 2) ^ ((row & 7) << 4);
    *(f16x2*)((char*)zn + byte) = pz;
    *(f16x2*)((char*)on + byte) = po;
  }
  __syncthreads();

  const int g = lane >> 4, ln16 = lane & 15;
  const f16* __restrict__ wg = wq3;
  const f16* __restrict__ wo = wq3 + (size_t)CH * CH;
#pragma unroll
  for (int mt = 0; mt < 4; mt++) {
    const int m0 = mt * 16;
    f16x8 az[4], ao[4];
#pragma unroll
    for (int ks = 0; ks < 4; ks++) {
      const int row = m0 + ln16;
      const int byte = (row * 256 + (ks * 32 + g * 8) * 2) ^ ((row & 7) << 4);
      az[ks] = *(const f16x8*)((const char*)zn + byte);
      ao[ks] = *(const f16x8*)((const char*)on + byte);
    }
#pragma unroll
    for (int f = 0; f < 2; f++) {
      const int col = w * 32 + f * 16 + ln16;  // output channel
      f32x4 accG = {0.f, 0.f, 0.f, 0.f}, accP = {0.f, 0.f, 0.f, 0.f};
#pragma unroll
      for (int ks = 0; ks < 4; ks++) {
        const size_t woff = (size_t)col * CH + ks * 32 + g * 8;
        const f16x8 bg = *(const f16x8*)(wg + woff);
        const f16x8 bo = *(const f16x8*)(wo + woff);
        accG = __builtin_amdgcn_mfma_f32_16x16x32_f16(az[ks], bg, accG, 0, 0, 0);
        accP = __builtin_amdgcn_mfma_f32_16x16x32_f16(ao[ks], bo, accP, 0, 0, 0);
      }
#pragma unroll
      for (int reg = 0; reg < 4; reg++) {
        const int row = m0 + g * 4 + reg;
        const float v = sigmoidf_(accG[reg]) * accP[reg];
        const int byte = (row * 512 + col * 4) ^ ((row & 7) << 4);
        *(float*)((char*)res + byte) = v;
      }
    }
  }
  __syncthreads();

  const int row = t >> 2, q = t & 3;
  float* __restrict__ dst = out + (r0 + row) * CH + q * 32;
#pragma unroll
  for (int e = 0; e < 8; e++) {
    const int byte = (row * 512 + q * 128 + e * 16) ^ ((row & 7) << 4);
    *(float4*)(dst + e * 4) = *(const float4*)((const char*)res + byte);
  }
}

extern "C" void kernel_launch(void* const* d_in, const int* in_sizes, int n_in,
                              void* d_out, int out_size, void* d_ws, size_t ws_size,
                              hipStream_t stream) {
  const float* z = (const float*)d_in[0];
  const float* pm = (const float*)d_in[1];
  const float* ln_in_w = (const float*)d_in[2];
  const float* ln_in_b = (const float*)d_in[3];
  const float* ln_out_w = (const float*)d_in[4];
  const float* ln_out_b = (const float*)d_in[5];
  const float* w_pa = (const float*)d_in[6];
  const float* w_pb = (const float*)d_in[7];
  const float* w_ga = (const float*)d_in[8];
  const float* w_gb = (const float*)d_in[9];
  const float* w_g = (const float*)d_in[10];
  const float* w_o = (const float*)d_in[11];

  // ws: a_t | b_t (fp16, 64 MB each) = exactly 128 MB.
  // wq (pass1 weights fp16, 128 KB) lives at the START of d_out: written by
  // pass0, read by pass1, then d_out fully overwritten by pass2.
  // wq3 (pass3 weights fp16, 64 KB) lives at the START of ws (a_t region),
  // written by k_cvt2 AFTER pass2 has consumed a_t (same stream, serialized).
  f16* a_t = (f16*)d_ws;
  f16* b_t = a_t + (size_t)CH * NROW;
  float* out = (float*)d_out;
  f16* wq = (f16*)d_out;
  f16* wq3 = (f16*)d_ws;

  k_pass0<<<256, 256, 0, stream>>>(w_pa, w_ga, w_pb, w_gb, wq);
  k_pass1<<<4096, 256, 0, stream>>>(z, pm, ln_in_w, ln_in_b, wq, a_t, b_t);
  k_pass2<<<2048, 256, 0, stream>>>(a_t, b_t, out);
  k_cvt2<<<128, 256, 0, stream>>>(w_g, w_o, wq3);
  k_pass3<<<4096, 256, 0, stream>>>(z, ln_in_w, ln_in_b, ln_out_w, ln_out_b,
                                    wq3, out);
}

// Round 6
// 711.383 us; speedup vs baseline: 16.9196x; 1.1238x over previous
//
#include <hip/hip_runtime.h>
#include <hip/hip_fp16.h>

// TriangleMultiplicationOutgoing — MI355X (gfx950)
// ROUND 10: occupancy fixes for pass2 + pass3 (pass0/cvt2/pass1 untouched,
// verified round 9).
//   - pass2: BK=32 double-buffer, 80B-padded LDS rows (16B-aligned, uniform
//     bank groups -> conflict-free b128). LDS 64->40KB = 4 blocks/CU
//     (was 2). __launch_bounds__(256,4) pins VGPR <=128. Same verified
//     1-barrier reg-staged loop, 16 K-steps.
//   - pass3: res staging dropped (direct 64B/quarter-wave stores from acc),
//     fast LN shape from pass1 (16 lanes/row, float4, 4-deep butterfly),
//     weights hoisted per-f. LDS 64->32KB = 4 blocks/CU.

typedef unsigned short u16;
typedef unsigned int u32;
typedef unsigned short u16x8 __attribute__((ext_vector_type(8)));
typedef _Float16 f16;
typedef _Float16 f16x8 __attribute__((ext_vector_type(8)));
typedef _Float16 f16x2 __attribute__((ext_vector_type(2)));
typedef float f32x4 __attribute__((ext_vector_type(4)));

#define NROW 262144  // 512*512 spatial positions
#define CH 128

__device__ __forceinline__ float sigmoidf_(float x) {
  return 1.0f / (1.0f + __expf(-x));
}

// ---------------- pass 0: weights fp32 -> fp16, order [pa, ga, pb, gb] ------
__global__ __launch_bounds__(256) void k_pass0(
    const float* __restrict__ wpa, const float* __restrict__ wga,
    const float* __restrict__ wpb, const float* __restrict__ wgb,
    f16* __restrict__ wq) {
  const int m = blockIdx.x >> 6;                       // 64 blocks per matrix
  const int idx = ((blockIdx.x & 63) << 8) + threadIdx.x;
  const float* src = (m == 0) ? wpa : (m == 1) ? wga : (m == 2) ? wpb : wgb;
  wq[(size_t)m * CH * CH + idx] = (f16)src[idx];
}

// ---------------- cvt2: w_g, w_o fp32 -> fp16 (into ws head) ----------------
__global__ __launch_bounds__(256) void k_cvt2(
    const float* __restrict__ w_g, const float* __restrict__ w_o,
    f16* __restrict__ wq3) {
  const int m = blockIdx.x >> 6;                       // 64 blocks per matrix
  const int idx = ((blockIdx.x & 63) << 8) + threadIdx.x;
  const float* src = (m == 0) ? w_g : w_o;
  wq3[(size_t)m * CH * CH + idx] = (f16)src[idx];
}

// ---------------- pass 1: LN(z) + 4 projections -> a,b (fp16, [c][r]) -------
// UNCHANGED from verified round-9 build.
__global__ __launch_bounds__(256) void k_pass1(
    const float* __restrict__ z, const float* __restrict__ pm,
    const float* __restrict__ lnw, const float* __restrict__ lnb,
    const f16* __restrict__ wq,
    f16* __restrict__ a_t, f16* __restrict__ b_t) {
  __shared__ __attribute__((aligned(16))) f16 zn[64 * CH];  // 16 KB
  __shared__ __attribute__((aligned(16))) f16 ab[CH * 64];  // 16 KB (one pair)
  __shared__ float pmv[64];
  const int t = threadIdx.x, lane = t & 63, w = t >> 6;
  const size_t r0 = (size_t)blockIdx.x * 64;

  {
    const int rr = lane >> 4, q = lane & 15;
    const float4 lw0 = *(const float4*)(lnw + q * 8);
    const float4 lw1 = *(const float4*)(lnw + q * 8 + 4);
    const float4 lb0 = *(const float4*)(lnb + q * 8);
    const float4 lb1 = *(const float4*)(lnb + q * 8 + 4);
    for (int it = 0; it < 4; it++) {
      const int row = w * 16 + it * 4 + rr;
      const float* src = z + (r0 + row) * CH + q * 8;
      const float4 v0 = *(const float4*)(src);
      const float4 v1 = *(const float4*)(src + 4);
      float s = v0.x + v0.y + v0.z + v0.w + v1.x + v1.y + v1.z + v1.w;
      float sq = v0.x * v0.x + v0.y * v0.y + v0.z * v0.z + v0.w * v0.w +
                 v1.x * v1.x + v1.y * v1.y + v1.z * v1.z + v1.w * v1.w;
#pragma unroll
      for (int off = 8; off > 0; off >>= 1) {
        s += __shfl_xor(s, off);
        sq += __shfl_xor(sq, off);
      }
      const float mu = s * (1.0f / 128.0f);
      const float rs = rsqrtf(sq * (1.0f / 128.0f) - mu * mu + 1e-5f);
      f16x8 p;
      p[0] = (f16)((v0.x - mu) * rs * lw0.x + lb0.x);
      p[1] = (f16)((v0.y - mu) * rs * lw0.y + lb0.y);
      p[2] = (f16)((v0.z - mu) * rs * lw0.z + lb0.z);
      p[3] = (f16)((v0.w - mu) * rs * lw0.w + lb0.w);
      p[4] = (f16)((v1.x - mu) * rs * lw1.x + lb1.x);
      p[5] = (f16)((v1.y - mu) * rs * lw1.y + lb1.y);
      p[6] = (f16)((v1.z - mu) * rs * lw1.z + lb1.z);
      p[7] = (f16)((v1.w - mu) * rs * lw1.w + lb1.w);
      const int byte = (row * 256 + q * 16) ^ ((row & 7) << 4);
      *(f16x8*)((char*)zn + byte) = p;
      if (q == 0) pmv[row] = pm[r0 + row];
    }
  }
  __syncthreads();

  const int g = lane >> 4, ln16 = lane & 15;
#pragma unroll
  for (int pair = 0; pair < 2; pair++) {  // 0:(pa,ga)->a  1:(pb,gb)->b
    const f16* __restrict__ wp = wq + (size_t)(pair * 2 + 0) * CH * CH;
    const f16* __restrict__ wgp = wq + (size_t)(pair * 2 + 1) * CH * CH;
#pragma unroll
    for (int f = 0; f < 2; f++) {
      const int col = w * 32 + f * 16 + ln16;  // output channel
      f16x8 bp[4], bg[4];
#pragma unroll
      for (int ks = 0; ks < 4; ks++) {
        const size_t wo = (size_t)col * CH + ks * 32 + g * 8;
        bp[ks] = *(const f16x8*)(wp + wo);
        bg[ks] = *(const f16x8*)(wgp + wo);
      }
#pragma unroll
      for (int mt = 0; mt < 4; mt++) {
        const int m0 = mt * 16;
        const int row = m0 + ln16;
        f32x4 accP = {0.f, 0.f, 0.f, 0.f}, accG = {0.f, 0.f, 0.f, 0.f};
#pragma unroll
        for (int ks = 0; ks < 4; ks++) {
          const int byte =
              (row * 256 + (ks * 32 + g * 8) * 2) ^ ((row & 7) << 4);
          const f16x8 af = *(const f16x8*)((const char*)zn + byte);
          accP = __builtin_amdgcn_mfma_f32_16x16x32_f16(af, bp[ks], accP, 0, 0, 0);
          accG = __builtin_amdgcn_mfma_f32_16x16x32_f16(af, bg[ks], accG, 0, 0, 0);
        }
        uint2 pk;
        {
          const int rbase = m0 + g * 4;
          const float v0 = pmv[rbase + 0] * sigmoidf_(accG[0]) * accP[0];
          const float v1 = pmv[rbase + 1] * sigmoidf_(accG[1]) * accP[1];
          const float v2 = pmv[rbase + 2] * sigmoidf_(accG[2]) * accP[2];
          const float v3 = pmv[rbase + 3] * sigmoidf_(accG[3]) * accP[3];
          f16x2 h01, h23;
          h01.x = (f16)v0; h01.y = (f16)v1;
          h23.x = (f16)v2; h23.y = (f16)v3;
          pk.x = *(u32*)&h01;
          pk.y = *(u32*)&h23;
        }
        const int byte =
            ((col * 64 + m0 + g * 4) * 2) ^ ((col & 7) << 4);
        *(uint2*)((char*)ab + byte) = pk;
      }
    }
    __syncthreads();
    {
      const int o = t >> 1, h = t & 1;
      f16* __restrict__ dst =
          (pair ? b_t : a_t) + (size_t)o * NROW + r0 + h * 32;
#pragma unroll
      for (int e = 0; e < 4; e++) {
        const int byte =
            ((o * 64 + h * 32 + e * 8) * 2) ^ ((o & 7) << 4);
        *(uint4*)(dst + e * 8) = *(const uint4*)((const char*)ab + byte);
      }
    }
    if (pair == 0) __syncthreads();  // ab reused by pair 1
  }
}

// ------- pass 2: o[i,j,c] = sum_k a[i,k,c]*b[j,k,c]  (MFMA fp16 GEMM) -------
// Per channel c: O_c(512x512) = A_c * B_c^T. Block: one c, one 128x128 tile.
// BK=32, 16 K-steps, double-buffered 80B-padded LDS (40KB -> 4 blocks/CU).
__global__ __launch_bounds__(256, 4) void k_pass2(
    const f16* __restrict__ a_t, const f16* __restrict__ b_t,
    float* __restrict__ o_rc) {
  // rows padded to 40 halfs (80 B = 5*16B): 16B-aligned, uniform bank groups.
  __shared__ __attribute__((aligned(16))) f16 At[2][128 * 40];  // 2x10 KB
  __shared__ __attribute__((aligned(16))) f16 Bt[2][128 * 40];  // 2x10 KB
  const int t = threadIdx.x, lane = t & 63, w = t >> 6;
  const int bx = blockIdx.x;
  const int xcd = bx & 7, s = bx >> 3;
  const int c = s & 127, T = xcd + ((s >> 7) << 3);
  const int i0 = (T >> 2) * 128, j0 = (T & 3) * 128;
  const int wr = w >> 1, wc = w & 1;          // wave quadrant
  const int g = lane >> 4, ln16 = lane & 15;

  const f16* __restrict__ Ab = a_t + (size_t)c * NROW + (size_t)i0 * 512;
  const f16* __restrict__ Bb = b_t + (size_t)c * NROW + (size_t)j0 * 512;

  // staging: thread t -> row t>>1 (0..127), half t&1 (16 halfs of k)
  const int srow = t >> 1, shalf = t & 1;
  const f16* __restrict__ gA = Ab + (size_t)srow * 512 + shalf * 16;
  const f16* __restrict__ gB = Bb + (size_t)srow * 512 + shalf * 16;
  const int wb = srow * 80 + shalf * 32;  // LDS byte base

  f32x4 acc[4][4];
#pragma unroll
  for (int mt = 0; mt < 4; mt++)
#pragma unroll
    for (int nt = 0; nt < 4; nt++) acc[mt][nt] = {0.f, 0.f, 0.f, 0.f};

  // prologue: stage K-step 0 into buf 0
  uint4 va0 = *(const uint4*)(gA), va1 = *(const uint4*)(gA + 8);
  uint4 vb0 = *(const uint4*)(gB), vb1 = *(const uint4*)(gB + 8);
  *(uint4*)((char*)At[0] + wb) = va0;
  *(uint4*)((char*)At[0] + wb + 16) = va1;
  *(uint4*)((char*)Bt[0] + wb) = vb0;
  *(uint4*)((char*)Bt[0] + wb + 16) = vb1;
  __syncthreads();

  for (int ks = 0; ks < 16; ks++) {
    const int buf = ks & 1;
    const bool more = (ks + 1) < 16;
    if (more) {  // issue next K-step's global loads early
      va0 = *(const uint4*)(gA + (ks + 1) * 32);
      va1 = *(const uint4*)(gA + (ks + 1) * 32 + 8);
      vb0 = *(const uint4*)(gB + (ks + 1) * 32);
      vb1 = *(const uint4*)(gB + (ks + 1) * 32 + 8);
    }
    f16x8 bfr[4];
#pragma unroll
    for (int nt = 0; nt < 4; nt++) {
      const int row = wc * 64 + nt * 16 + ln16;
      bfr[nt] = *(const f16x8*)((const char*)Bt[buf] + row * 80 + g * 16);
    }
#pragma unroll
    for (int mt = 0; mt < 4; mt++) {
      const int row = wr * 64 + mt * 16 + ln16;
      const f16x8 afr =
          *(const f16x8*)((const char*)At[buf] + row * 80 + g * 16);
#pragma unroll
      for (int nt = 0; nt < 4; nt++)
        acc[mt][nt] =
            __builtin_amdgcn_mfma_f32_16x16x32_f16(afr, bfr[nt], acc[mt][nt], 0, 0, 0);
    }
    if (more) {  // write next K-step late, after MFMA cluster
      *(uint4*)((char*)At[buf ^ 1] + wb) = va0;
      *(uint4*)((char*)At[buf ^ 1] + wb + 16) = va1;
      *(uint4*)((char*)Bt[buf ^ 1] + wb) = vb0;
      *(uint4*)((char*)Bt[buf ^ 1] + wb + 16) = vb1;
    }
    __syncthreads();
  }

  // epilogue: D layout col=ln16 (->j), row=g*4+reg (->i). Scatter 4B stores;
  // XCD clustering merges the 16-channel lines in L2.
#pragma unroll
  for (int mt = 0; mt < 4; mt++)
#pragma unroll
    for (int reg = 0; reg < 4; reg++) {
      const int i = i0 + wr * 64 + mt * 16 + g * 4 + reg;
#pragma unroll
      for (int nt = 0; nt < 4; nt++) {
        const int j = j0 + wc * 64 + nt * 16 + ln16;
        o_rc[((size_t)i * 512 + j) * CH + c] = acc[mt][nt][reg];
      }
    }
}

// ------- pass 3: out = sigmoid(zn@w_g^T) * (LN(o) @ w_o^T)  (MFMA fp16) -----
// 64 rows/block, 4096 blocks. In-place on d_out. No res staging: direct
// stores from accumulator (16-lane groups write 64B contiguous segments).
__global__ __launch_bounds__(256) void k_pass3(
    const float* __restrict__ z,
    const float* __restrict__ lnwi, const float* __restrict__ lnbi,
    const float* __restrict__ lnwo, const float* __restrict__ lnbo,
    const f16* __restrict__ wq3,  // [w_g | w_o] fp16, 128x128 each
    float* __restrict__ out) {
  __shared__ __attribute__((aligned(16))) f16 zn[64 * CH];  // 16 KB
  __shared__ __attribute__((aligned(16))) f16 on[64 * CH];  // 16 KB
  const int t = threadIdx.x, lane = t & 63, w = t >> 6;
  const size_t r0 = (size_t)blockIdx.x * 64;

  // Phase A: LN(z) and LN(o), 16 lanes/row x 8ch/lane, 4-deep butterfly.
  {
    const int rr = lane >> 4, q = lane & 15;
    const float4 lwi0 = *(const float4*)(lnwi + q * 8);
    const float4 lwi1 = *(const float4*)(lnwi + q * 8 + 4);
    const float4 lbi0 = *(const float4*)(lnbi + q * 8);
    const float4 lbi1 = *(const float4*)(lnbi + q * 8 + 4);
    const float4 lwo0 = *(const float4*)(lnwo + q * 8);
    const float4 lwo1 = *(const float4*)(lnwo + q * 8 + 4);
    const float4 lbo0 = *(const float4*)(lnbo + q * 8);
    const float4 lbo1 = *(const float4*)(lnbo + q * 8 + 4);
    for (int it = 0; it < 4; it++) {
      const int row = w * 16 + it * 4 + rr;
      const float* zs = z + (r0 + row) * CH + q * 8;
      const float* os = out + (r0 + row) * CH + q * 8;
      const float4 z0 = *(const float4*)(zs);
      const float4 z1 = *(const float4*)(zs + 4);
      const float4 o0 = *(const float4*)(os);
      const float4 o1 = *(const float4*)(os + 4);
      float s1 = z0.x + z0.y + z0.z + z0.w + z1.x + z1.y + z1.z + z1.w;
      float q1 = z0.x * z0.x + z0.y * z0.y + z0.z * z0.z + z0.w * z0.w +
                 z1.x * z1.x + z1.y * z1.y + z1.z * z1.z + z1.w * z1.w;
      float s2 = o0.x + o0.y + o0.z + o0.w + o1.x + o1.y + o1.z + o1.w;
      float q2 = o0.x * o0.x + o0.y * o0.y + o0.z * o0.z + o0.w * o0.w +
                 o1.x * o1.x + o1.y * o1.y + o1.z * o1.z + o1.w * o1.w;
#pragma unroll
      for (int off = 8; off > 0; off >>= 1) {
        s1 += __shfl_xor(s1, off);
        q1 += __shfl_xor(q1, off);
        s2 += __shfl_xor(s2, off);
        q2 += __shfl_xor(q2, off);
      }
      const float mu1 = s1 * (1.0f / 128.0f);
      const float rs1 = rsqrtf(q1 * (1.0f / 128.0f) - mu1 * mu1 + 1e-5f);
      const float mu2 = s2 * (1.0f / 128.0f);
      const float rs2 = rsqrtf(q2 * (1.0f / 128.0f) - mu2 * mu2 + 1e-5f);
      f16x8 pz, po;
      pz[0] = (f16)((z0.x - mu1) * rs1 * lwi0.x + lbi0.x);
      pz[1] = (f16)((z0.y - mu1) * rs1 * lwi0.y + lbi0.y);
      pz[2] = (f16)((z0.z - mu1) * rs1 * lwi0.z + lbi0.z);
      pz[3] = (f16)((z0.w - mu1) * rs1 * lwi0.w + lbi0.w);
      pz[4] = (f16)((z1.x - mu1) * rs1 * lwi1.x + lbi1.x);
      pz[5] = (f16)((z1.y - mu1) * rs1 * lwi1.y + lbi1.y);
      pz[6] = (f16)((z1.z - mu1) * rs1 * lwi1.z + lbi1.z);
      pz[7] = (f16)((z1.w - mu1) * rs1 * lwi1.w + lbi1.w);
      po[0] = (f16)((o0.x - mu2) * rs2 * lwo0.x + lbo0.x);
      po[1] = (f16)((o0.y - mu2) * rs2 * lwo0.y + lbo0.y);
      po[2] = (f16)((o0.z - mu2) * rs2 * lwo0.z + lbo0.z);
      po[3] = (f16)((o0.w - mu2) * rs2 * lwo0.w + lbo0.w);
      po[4] = (f16)((o1.x - mu2) * rs2 * lwo1.x + lbo1.x);
      po[5] = (f16)((o1.y - mu2) * rs2 * lwo1.y + lbo1.y);
      po[6] = (f16)((o1.z - mu2) * rs2 * lwo1.z + lbo1.z);
      po[7] = (f16)((o1.w - mu2) * rs2 * lwo1.w + lbo1.w);
      const int byte = (row * 256 + q * 16) ^ ((row & 7) << 4);
      *(f16x8*)((char*)zn + byte) = pz;
      *(f16x8*)((char*)on + byte) = po;
    }
  }
  __syncthreads();

  // Phase B: MFMA gate+proj with per-f hoisted weights; direct stores.
  const int g = lane >> 4, ln16 = lane & 15;
  const f16* __restrict__ wg = wq3;
  const f16* __restrict__ wo = wq3 + (size_t)CH * CH;
#pragma unroll
  for (int f = 0; f < 2; f++) {
    const int col = w * 32 + f * 16 + ln16;  // output channel
    f16x8 bg[4], bo[4];
#pragma unroll
    for (int ks = 0; ks < 4; ks++) {
      const size_t woff = (size_t)col * CH + ks * 32 + g * 8;
      bg[ks] = *(const f16x8*)(wg + woff);
      bo[ks] = *(const f16x8*)(wo + woff);
    }
#pragma unroll
    for (int mt = 0; mt < 4; mt++) {
      const int m0 = mt * 16;
      const int row = m0 + ln16;
      f32x4 accG = {0.f, 0.f, 0.f, 0.f}, accP = {0.f, 0.f, 0.f, 0.f};
#pragma unroll
      for (int ks = 0; ks < 4; ks++) {
        const int byte =
            (row * 256 + (ks * 32 + g * 8) * 2) ^ ((row & 7) << 4);
        const f16x8 az = *(const f16x8*)((const char*)zn + byte);
        const f16x8 ao = *(const f16x8*)((const char*)on + byte);
        accG = __builtin_amdgcn_mfma_f32_16x16x32_f16(az, bg[ks], accG, 0, 0, 0);
        accP = __builtin_amdgcn_mfma_f32_16x16x32_f16(ao, bo[ks], accP, 0, 0, 0);
      }
      // D layout: col=ln16, rows m0+g*4+reg. 16-lane groups store 64B rows.
#pragma unroll
      for (int reg = 0; reg < 4; reg++) {
        const int orow = m0 + g * 4 + reg;
        out[(r0 + orow) * CH + col] = sigmoidf_(accG[reg]) * accP[reg];
      }
    }
  }
}

extern "C" void kernel_launch(void* const* d_in, const int* in_sizes, int n_in,
                              void* d_out, int out_size, void* d_ws, size_t ws_size,
                              hipStream_t stream) {
  const float* z = (const float*)d_in[0];
  const float* pm = (const float*)d_in[1];
  const float* ln_in_w = (const float*)d_in[2];
  const float* ln_in_b = (const float*)d_in[3];
  const float* ln_out_w = (const float*)d_in[4];
  const float* ln_out_b = (const float*)d_in[5];
  const float* w_pa = (const float*)d_in[6];
  const float* w_pb = (const float*)d_in[7];
  const float* w_ga = (const float*)d_in[8];
  const float* w_gb = (const float*)d_in[9];
  const float* w_g = (const float*)d_in[10];
  const float* w_o = (const float*)d_in[11];

  // ws: a_t | b_t (fp16, 64 MB each) = exactly 128 MB.
  // wq (pass1 weights fp16, 128 KB) lives at the START of d_out: written by
  // pass0, read by pass1, then d_out fully overwritten by pass2.
  // wq3 (pass3 weights fp16, 64 KB) lives at the START of ws (a_t region),
  // written by k_cvt2 AFTER pass2 has consumed a_t (same stream, serialized).
  f16* a_t = (f16*)d_ws;
  f16* b_t = a_t + (size_t)CH * NROW;
  float* out = (float*)d_out;
  f16* wq = (f16*)d_out;
  f16* wq3 = (f16*)d_ws;

  k_pass0<<<256, 256, 0, stream>>>(w_pa, w_ga, w_pb, w_gb, wq);
  k_pass1<<<4096, 256, 0, stream>>>(z, pm, ln_in_w, ln_in_b, wq, a_t, b_t);
  k_pass2<<<2048, 256, 0, stream>>>(a_t, b_t, out);
  k_cvt2<<<128, 256, 0, stream>>>(w_g, w_o, wq3);
  k_pass3<<<4096, 256, 0, stream>>>(z, ln_in_w, ln_in_b, ln_out_w, ln_out_b,
                                    wq3, out);
}

// Round 7
// 652.819 us; speedup vs baseline: 18.4375x; 1.0897x over previous
//
#include <hip/hip_runtime.h>
#include <hip/hip_fp16.h>

// TriangleMultiplicationOutgoing — MI355X (gfx950)
// ROUND 11: pass2 traffic fix + pass3 split. (pass0/cvt2/pass1 untouched.)
//   - pass2: writes o16 fp16 CHANNEL-MAJOR into d_out (block-private regions,
//     full-sector stores; write amp gone). Bijective XCD remap: all 16 tiles
//     of a channel consecutive on ONE XCD -> panels HBM-fetched once (~1MB/ch
//     vs 4MB L2). Inner loop = verified round-8 BK=64 XOR-swizzled layout
//     (0 conflicts), single-buffered 32KB (4 blocks/CU), T14 reg staging,
//     LDS-staged coalesced epilogue.
//   - pass3a: transpose-read o16 via LDS, LN(o) -> on_t fp16 [r][c] in ws
//     (b_t region, dead after pass2).
//   - pass3b: round-10 pass3 with o-LN replaced by coalesced on_t load.
// d_out lifecycle: wq(128KB) -> o16(64MB, overwrites wq) -> final out(128MB).
// ws lifecycle: a_t|b_t (128MB) -> wq3(64KB @a_t) + on_t(64MB @b_t).

typedef unsigned short u16;
typedef unsigned int u32;
typedef unsigned short u16x8 __attribute__((ext_vector_type(8)));
typedef _Float16 f16;
typedef _Float16 f16x8 __attribute__((ext_vector_type(8)));
typedef _Float16 f16x2 __attribute__((ext_vector_type(2)));
typedef float f32x4 __attribute__((ext_vector_type(4)));

#define NROW 262144  // 512*512 spatial positions
#define CH 128

__device__ __forceinline__ float sigmoidf_(float x) {
  return 1.0f / (1.0f + __expf(-x));
}

// ---------------- pass 0: weights fp32 -> fp16, order [pa, ga, pb, gb] ------
__global__ __launch_bounds__(256) void k_pass0(
    const float* __restrict__ wpa, const float* __restrict__ wga,
    const float* __restrict__ wpb, const float* __restrict__ wgb,
    f16* __restrict__ wq) {
  const int m = blockIdx.x >> 6;
  const int idx = ((blockIdx.x & 63) << 8) + threadIdx.x;
  const float* src = (m == 0) ? wpa : (m == 1) ? wga : (m == 2) ? wpb : wgb;
  wq[(size_t)m * CH * CH + idx] = (f16)src[idx];
}

// ---------------- cvt2: w_g, w_o fp32 -> fp16 (into ws head) ----------------
__global__ __launch_bounds__(256) void k_cvt2(
    const float* __restrict__ w_g, const float* __restrict__ w_o,
    f16* __restrict__ wq3) {
  const int m = blockIdx.x >> 6;
  const int idx = ((blockIdx.x & 63) << 8) + threadIdx.x;
  const float* src = (m == 0) ? w_g : w_o;
  wq3[(size_t)m * CH * CH + idx] = (f16)src[idx];
}

// ---------------- pass 1: LN(z) + 4 projections -> a,b (fp16, [c][r]) -------
// UNCHANGED from verified round-9 build.
__global__ __launch_bounds__(256) void k_pass1(
    const float* __restrict__ z, const float* __restrict__ pm,
    const float* __restrict__ lnw, const float* __restrict__ lnb,
    const f16* __restrict__ wq,
    f16* __restrict__ a_t, f16* __restrict__ b_t) {
  __shared__ __attribute__((aligned(16))) f16 zn[64 * CH];  // 16 KB
  __shared__ __attribute__((aligned(16))) f16 ab[CH * 64];  // 16 KB (one pair)
  __shared__ float pmv[64];
  const int t = threadIdx.x, lane = t & 63, w = t >> 6;
  const size_t r0 = (size_t)blockIdx.x * 64;

  {
    const int rr = lane >> 4, q = lane & 15;
    const float4 lw0 = *(const float4*)(lnw + q * 8);
    const float4 lw1 = *(const float4*)(lnw + q * 8 + 4);
    const float4 lb0 = *(const float4*)(lnb + q * 8);
    const float4 lb1 = *(const float4*)(lnb + q * 8 + 4);
    for (int it = 0; it < 4; it++) {
      const int row = w * 16 + it * 4 + rr;
      const float* src = z + (r0 + row) * CH + q * 8;
      const float4 v0 = *(const float4*)(src);
      const float4 v1 = *(const float4*)(src + 4);
      float s = v0.x + v0.y + v0.z + v0.w + v1.x + v1.y + v1.z + v1.w;
      float sq = v0.x * v0.x + v0.y * v0.y + v0.z * v0.z + v0.w * v0.w +
                 v1.x * v1.x + v1.y * v1.y + v1.z * v1.z + v1.w * v1.w;
#pragma unroll
      for (int off = 8; off > 0; off >>= 1) {
        s += __shfl_xor(s, off);
        sq += __shfl_xor(sq, off);
      }
      const float mu = s * (1.0f / 128.0f);
      const float rs = rsqrtf(sq * (1.0f / 128.0f) - mu * mu + 1e-5f);
      f16x8 p;
      p[0] = (f16)((v0.x - mu) * rs * lw0.x + lb0.x);
      p[1] = (f16)((v0.y - mu) * rs * lw0.y + lb0.y);
      p[2] = (f16)((v0.z - mu) * rs * lw0.z + lb0.z);
      p[3] = (f16)((v0.w - mu) * rs * lw0.w + lb0.w);
      p[4] = (f16)((v1.x - mu) * rs * lw1.x + lb1.x);
      p[5] = (f16)((v1.y - mu) * rs * lw1.y + lb1.y);
      p[6] = (f16)((v1.z - mu) * rs * lw1.z + lb1.z);
      p[7] = (f16)((v1.w - mu) * rs * lw1.w + lb1.w);
      const int byte = (row * 256 + q * 16) ^ ((row & 7) << 4);
      *(f16x8*)((char*)zn + byte) = p;
      if (q == 0) pmv[row] = pm[r0 + row];
    }
  }
  __syncthreads();

  const int g = lane >> 4, ln16 = lane & 15;
#pragma unroll
  for (int pair = 0; pair < 2; pair++) {
    const f16* __restrict__ wp = wq + (size_t)(pair * 2 + 0) * CH * CH;
    const f16* __restrict__ wgp = wq + (size_t)(pair * 2 + 1) * CH * CH;
#pragma unroll
    for (int f = 0; f < 2; f++) {
      const int col = w * 32 + f * 16 + ln16;
      f16x8 bp[4], bg[4];
#pragma unroll
      for (int ks = 0; ks < 4; ks++) {
        const size_t wo = (size_t)col * CH + ks * 32 + g * 8;
        bp[ks] = *(const f16x8*)(wp + wo);
        bg[ks] = *(const f16x8*)(wgp + wo);
      }
#pragma unroll
      for (int mt = 0; mt < 4; mt++) {
        const int m0 = mt * 16;
        const int row = m0 + ln16;
        f32x4 accP = {0.f, 0.f, 0.f, 0.f}, accG = {0.f, 0.f, 0.f, 0.f};
#pragma unroll
        for (int ks = 0; ks < 4; ks++) {
          const int byte =
              (row * 256 + (ks * 32 + g * 8) * 2) ^ ((row & 7) << 4);
          const f16x8 af = *(const f16x8*)((const char*)zn + byte);
          accP = __builtin_amdgcn_mfma_f32_16x16x32_f16(af, bp[ks], accP, 0, 0, 0);
          accG = __builtin_amdgcn_mfma_f32_16x16x32_f16(af, bg[ks], accG, 0, 0, 0);
        }
        uint2 pk;
        {
          const int rbase = m0 + g * 4;
          const float v0 = pmv[rbase + 0] * sigmoidf_(accG[0]) * accP[0];
          const float v1 = pmv[rbase + 1] * sigmoidf_(accG[1]) * accP[1];
          const float v2 = pmv[rbase + 2] * sigmoidf_(accG[2]) * accP[2];
          const float v3 = pmv[rbase + 3] * sigmoidf_(accG[3]) * accP[3];
          f16x2 h01, h23;
          h01.x = (f16)v0; h01.y = (f16)v1;
          h23.x = (f16)v2; h23.y = (f16)v3;
          pk.x = *(u32*)&h01;
          pk.y = *(u32*)&h23;
        }
        const int byte = ((col * 64 + m0 + g * 4) * 2) ^ ((col & 7) << 4);
        *(uint2*)((char*)ab + byte) = pk;
      }
    }
    __syncthreads();
    {
      const int o = t >> 1, h = t & 1;
      f16* __restrict__ dst =
          (pair ? b_t : a_t) + (size_t)o * NROW + r0 + h * 32;
#pragma unroll
      for (int e = 0; e < 4; e++) {
        const int byte = ((o * 64 + h * 32 + e * 8) * 2) ^ ((o & 7) << 4);
        *(uint4*)(dst + e * 8) = *(const uint4*)((const char*)ab + byte);
      }
    }
    if (pair == 0) __syncthreads();
  }
}

// ------- pass 2: o16[c][i,j] = sum_k a[i,k,c]*b[j,k,c]  (MFMA fp16 GEMM) ----
// Per channel c: O_c(512x512) = A_c * B_c^T, output fp16 channel-major.
// Remap: xcd=bx&7, c = xcd + 8*(k>>4), T = k&15 -> all 16 tiles of a channel
// consecutive on one XCD (panels L2-resident, fetched once).
__global__ __launch_bounds__(256, 4) void k_pass2(
    const f16* __restrict__ a_t, const f16* __restrict__ b_t,
    f16* __restrict__ o16) {
  __shared__ __attribute__((aligned(16))) f16 smem[2 * 128 * 64];  // 32 KB
  f16* At = smem;              // 128 rows x 64 halfs (XOR-swizzled)
  f16* Bt = smem + 128 * 64;
  const int t = threadIdx.x, lane = t & 63, w = t >> 6;
  const int bx = blockIdx.x;
  const int xcd = bx & 7, k = bx >> 3;
  const int T = k & 15, cc = k >> 4;
  const int c = xcd + (cc << 3);
  const int i0 = (T >> 2) * 128, j0 = (T & 3) * 128;
  const int wr = w >> 1, wc = w & 1;
  const int g = lane >> 4, ln16 = lane & 15;

  const f16* __restrict__ Ab = a_t + (size_t)c * NROW + (size_t)i0 * 512;
  const f16* __restrict__ Bb = b_t + (size_t)c * NROW + (size_t)j0 * 512;

  // staging: thread t -> row t>>1 (0..127), half t&1 (32 halfs of k)
  const int srow = t >> 1, shalf = t & 1;
  const f16* __restrict__ gA = Ab + (size_t)srow * 512 + shalf * 32;
  const f16* __restrict__ gB = Bb + (size_t)srow * 512 + shalf * 32;
  int swb[4];
#pragma unroll
  for (int q = 0; q < 4; q++)
    swb[q] = srow * 128 + ((shalf * 64 + q * 16) ^ ((srow & 7) << 4));

  f32x4 acc[4][4];
#pragma unroll
  for (int mt = 0; mt < 4; mt++)
#pragma unroll
    for (int nt = 0; nt < 4; nt++) acc[mt][nt] = {0.f, 0.f, 0.f, 0.f};

  uint4 va[4], vb[4];
#pragma unroll
  for (int q = 0; q < 4; q++) {
    va[q] = *(const uint4*)(gA + q * 8);
    vb[q] = *(const uint4*)(gB + q * 8);
  }
#pragma unroll
  for (int q = 0; q < 4; q++) {
    *(uint4*)((char*)At + swb[q]) = va[q];
    *(uint4*)((char*)Bt + swb[q]) = vb[q];
  }
  __syncthreads();

  for (int ks = 0; ks < 8; ks++) {
    const bool more = (ks + 1) < 8;
    if (more) {  // issue next K-step's global loads early (T14)
#pragma unroll
      for (int q = 0; q < 4; q++) {
        va[q] = *(const uint4*)(gA + (ks + 1) * 64 + q * 8);
        vb[q] = *(const uint4*)(gB + (ks + 1) * 64 + q * 8);
      }
    }
    f16x8 bfr[4][2];
#pragma unroll
    for (int nt = 0; nt < 4; nt++)
#pragma unroll
      for (int kk = 0; kk < 2; kk++) {
        const int row = wc * 64 + nt * 16 + ln16;
        const int byte = row * 128 + ((kk * 64 + g * 16) ^ ((row & 7) << 4));
        bfr[nt][kk] = *(const f16x8*)((const char*)Bt + byte);
      }
#pragma unroll
    for (int mt = 0; mt < 4; mt++) {
      f16x8 afr[2];
#pragma unroll
      for (int kk = 0; kk < 2; kk++) {
        const int row = wr * 64 + mt * 16 + ln16;
        const int byte = row * 128 + ((kk * 64 + g * 16) ^ ((row & 7) << 4));
        afr[kk] = *(const f16x8*)((const char*)At + byte);
      }
#pragma unroll
      for (int nt = 0; nt < 4; nt++) {
        acc[mt][nt] =
            __builtin_amdgcn_mfma_f32_16x16x32_f16(afr[0], bfr[nt][0], acc[mt][nt], 0, 0, 0);
        acc[mt][nt] =
            __builtin_amdgcn_mfma_f32_16x16x32_f16(afr[1], bfr[nt][1], acc[mt][nt], 0, 0, 0);
      }
    }
    __syncthreads();  // all reads done before LDS overwrite
    if (more) {
#pragma unroll
      for (int q = 0; q < 4; q++) {
        *(uint4*)((char*)At + swb[q]) = va[q];
        *(uint4*)((char*)Bt + swb[q]) = vb[q];
      }
      __syncthreads();
    }
  }

  // epilogue: stage 128x128 fp16 tile in LDS (reuse smem), coalesced stores.
  f16* otile = smem;
#pragma unroll
  for (int mt = 0; mt < 4; mt++)
#pragma unroll
    for (int reg = 0; reg < 4; reg++) {
      const int il = wr * 64 + mt * 16 + g * 4 + reg;
#pragma unroll
      for (int nt = 0; nt < 4; nt++) {
        const int jl = wc * 64 + nt * 16 + ln16;
        const int byte = (il * 256 + jl * 2) ^ ((il & 7) << 4);
        *(f16*)((char*)otile + byte) = (f16)acc[mt][nt][reg];
      }
    }
  __syncthreads();
  {
    const int i = t >> 1, jh = t & 1;
    f16* __restrict__ dst =
        o16 + (size_t)c * NROW + (size_t)(i0 + i) * 512 + j0 + jh * 64;
#pragma unroll
    for (int e = 0; e < 8; e++) {
      const int byte = (i * 256 + jh * 128 + e * 16) ^ ((i & 7) << 4);
      *(uint4*)(dst + e * 8) = *(const uint4*)((const char*)otile + byte);
    }
  }
}

// ------- pass 3a: on_t[r][c] = LN_c(o16[c][r])  (transpose via LDS) ---------
__global__ __launch_bounds__(256) void k_pass3a(
    const f16* __restrict__ o16,
    const float* __restrict__ lnwo, const float* __restrict__ lnbo,
    f16* __restrict__ on_t) {
  __shared__ __attribute__((aligned(16))) f16 ot[64 * CH];  // 16 KB
  const int t = threadIdx.x, lane = t & 63, w = t >> 6;
  const size_t r0 = (size_t)blockIdx.x * 64;

  // load transposed: thread t -> channel c = t>>1, rows (t&1)*32..+31 (64 B)
  {
    const int c = t >> 1, rh = t & 1;
    const f16* src = o16 + (size_t)c * NROW + r0 + rh * 32;
    u16x8 d[4];
#pragma unroll
    for (int q = 0; q < 4; q++) d[q] = *(const u16x8*)((const u16*)src + q * 8);
#pragma unroll
    for (int i = 0; i < 32; i++) {
      const int r = rh * 32 + i;
      const int byte = (r * 256 + c * 2) ^ ((r & 7) << 4);
      *(u16*)((char*)ot + byte) = d[i >> 3][i & 7];
    }
  }
  __syncthreads();

  // LN over c: 16 lanes/row x 8 ch/lane, 4-level butterfly.
  {
    const int rr = lane >> 4, q = lane & 15;
    const float4 lw0 = *(const float4*)(lnwo + q * 8);
    const float4 lw1 = *(const float4*)(lnwo + q * 8 + 4);
    const float4 lb0 = *(const float4*)(lnbo + q * 8);
    const float4 lb1 = *(const float4*)(lnbo + q * 8 + 4);
    for (int it = 0; it < 4; it++) {
      const int row = w * 16 + it * 4 + rr;
      const int byte = (row * 256 + q * 16) ^ ((row & 7) << 4);
      const f16x8 v = *(const f16x8*)((const char*)ot + byte);
      float x[8];
#pragma unroll
      for (int e = 0; e < 8; e++) x[e] = (float)v[e];
      float s = 0.f, sq = 0.f;
#pragma unroll
      for (int e = 0; e < 8; e++) { s += x[e]; sq += x[e] * x[e]; }
#pragma unroll
      for (int off = 8; off > 0; off >>= 1) {
        s += __shfl_xor(s, off);
        sq += __shfl_xor(sq, off);
      }
      const float mu = s * (1.0f / 128.0f);
      const float rs = rsqrtf(sq * (1.0f / 128.0f) - mu * mu + 1e-5f);
      f16x8 p;
      p[0] = (f16)((x[0] - mu) * rs * lw0.x + lb0.x);
      p[1] = (f16)((x[1] - mu) * rs * lw0.y + lb0.y);
      p[2] = (f16)((x[2] - mu) * rs * lw0.z + lb0.z);
      p[3] = (f16)((x[3] - mu) * rs * lw0.w + lb0.w);
      p[4] = (f16)((x[4] - mu) * rs * lw1.x + lb1.x);
      p[5] = (f16)((x[5] - mu) * rs * lw1.y + lb1.y);
      p[6] = (f16)((x[6] - mu) * rs * lw1.z + lb1.z);
      p[7] = (f16)((x[7] - mu) * rs * lw1.w + lb1.w);
      *(f16x8*)(on_t + (r0 + row) * CH + q * 8) = p;
    }
  }
}

// ------- pass 3b: out = sigmoid(LN(z)@w_g^T) * (on @ w_o^T)  (MFMA fp16) ----
__global__ __launch_bounds__(256) void k_pass3b(
    const float* __restrict__ z,
    const float* __restrict__ lnwi, const float* __restrict__ lnbi,
    const f16* __restrict__ on_t,
    const f16* __restrict__ wq3,  // [w_g | w_o] fp16, 128x128 each
    float* __restrict__ out) {
  __shared__ __attribute__((aligned(16))) f16 zn[64 * CH];  // 16 KB
  __shared__ __attribute__((aligned(16))) f16 on[64 * CH];  // 16 KB
  const int t = threadIdx.x, lane = t & 63, w = t >> 6;
  const size_t r0 = (size_t)blockIdx.x * 64;

  // Phase A1: coalesced load of on_t tile into swizzled LDS.
  {
    const int row = t >> 2, ch0 = (t & 3) * 32;
    const u16* src = (const u16*)(on_t + (r0 + row) * CH + ch0);
#pragma unroll
    for (int e = 0; e < 4; e++) {
      const uint4 v = *(const uint4*)(src + e * 8);
      const int byte = (row * 256 + (ch0 + e * 8) * 2) ^ ((row & 7) << 4);
      *(uint4*)((char*)on + byte) = v;
    }
  }
  // Phase A2: LN(z), 16 lanes/row x 8ch/lane, 4-deep butterfly.
  {
    const int rr = lane >> 4, q = lane & 15;
    const float4 lw0 = *(const float4*)(lnwi + q * 8);
    const float4 lw1 = *(const float4*)(lnwi + q * 8 + 4);
    const float4 lb0 = *(const float4*)(lnbi + q * 8);
    const float4 lb1 = *(const float4*)(lnbi + q * 8 + 4);
    for (int it = 0; it < 4; it++) {
      const int row = w * 16 + it * 4 + rr;
      const float* src = z + (r0 + row) * CH + q * 8;
      const float4 v0 = *(const float4*)(src);
      const float4 v1 = *(const float4*)(src + 4);
      float s = v0.x + v0.y + v0.z + v0.w + v1.x + v1.y + v1.z + v1.w;
      float sq = v0.x * v0.x + v0.y * v0.y + v0.z * v0.z + v0.w * v0.w +
                 v1.x * v1.x + v1.y * v1.y + v1.z * v1.z + v1.w * v1.w;
#pragma unroll
      for (int off = 8; off > 0; off >>= 1) {
        s += __shfl_xor(s, off);
        sq += __shfl_xor(sq, off);
      }
      const float mu = s * (1.0f / 128.0f);
      const float rs = rsqrtf(sq * (1.0f / 128.0f) - mu * mu + 1e-5f);
      f16x8 p;
      p[0] = (f16)((v0.x - mu) * rs * lw0.x + lb0.x);
      p[1] = (f16)((v0.y - mu) * rs * lw0.y + lb0.y);
      p[2] = (f16)((v0.z - mu) * rs * lw0.z + lb0.z);
      p[3] = (f16)((v0.w - mu) * rs * lw0.w + lb0.w);
      p[4] = (f16)((v1.x - mu) * rs * lw1.x + lb1.x);
      p[5] = (f16)((v1.y - mu) * rs * lw1.y + lb1.y);
      p[6] = (f16)((v1.z - mu) * rs * lw1.z + lb1.z);
      p[7] = (f16)((v1.w - mu) * rs * lw1.w + lb1.w);
      const int byte = (row * 256 + q * 16) ^ ((row & 7) << 4);
      *(f16x8*)((char*)zn + byte) = p;
    }
  }
  __syncthreads();

  // Phase B: MFMA gate+proj with per-f hoisted weights; direct stores.
  const int g = lane >> 4, ln16 = lane & 15;
  const f16* __restrict__ wg = wq3;
  const f16* __restrict__ wo = wq3 + (size_t)CH * CH;
#pragma unroll
  for (int f = 0; f < 2; f++) {
    const int col = w * 32 + f * 16 + ln16;
    f16x8 bg[4], bo[4];
#pragma unroll
    for (int ks = 0; ks < 4; ks++) {
      const size_t woff = (size_t)col * CH + ks * 32 + g * 8;
      bg[ks] = *(const f16x8*)(wg + woff);
      bo[ks] = *(const f16x8*)(wo + woff);
    }
#pragma unroll
    for (int mt = 0; mt < 4; mt++) {
      const int m0 = mt * 16;
      const int row = m0 + ln16;
      f32x4 accG = {0.f, 0.f, 0.f, 0.f}, accP = {0.f, 0.f, 0.f, 0.f};
#pragma unroll
      for (int ks = 0; ks < 4; ks++) {
        const int byte =
            (row * 256 + (ks * 32 + g * 8) * 2) ^ ((row & 7) << 4);
        const f16x8 az = *(const f16x8*)((const char*)zn + byte);
        const f16x8 ao = *(const f16x8*)((const char*)on + byte);
        accG = __builtin_amdgcn_mfma_f32_16x16x32_f16(az, bg[ks], accG, 0, 0, 0);
        accP = __builtin_amdgcn_mfma_f32_16x16x32_f16(ao, bo[ks], accP, 0, 0, 0);
      }
#pragma unroll
      for (int reg = 0; reg < 4; reg++) {
        const int orow = m0 + g * 4 + reg;
        out[(r0 + orow) * CH + col] = sigmoidf_(accG[reg]) * accP[reg];
      }
    }
  }
}

extern "C" void kernel_launch(void* const* d_in, const int* in_sizes, int n_in,
                              void* d_out, int out_size, void* d_ws, size_t ws_size,
                              hipStream_t stream) {
  const float* z = (const float*)d_in[0];
  const float* pm = (const float*)d_in[1];
  const float* ln_in_w = (const float*)d_in[2];
  const float* ln_in_b = (const float*)d_in[3];
  const float* ln_out_w = (const float*)d_in[4];
  const float* ln_out_b = (const float*)d_in[5];
  const float* w_pa = (const float*)d_in[6];
  const float* w_pb = (const float*)d_in[7];
  const float* w_ga = (const float*)d_in[8];
  const float* w_gb = (const float*)d_in[9];
  const float* w_g = (const float*)d_in[10];
  const float* w_o = (const float*)d_in[11];

  // ws: a_t | b_t (fp16, 64 MB each). After pass2: wq3 @ws start, on_t @+64MB.
  // d_out: wq (128KB) -> o16 fp16 c-major (64MB) -> final out (128MB fp32).
  f16* a_t = (f16*)d_ws;
  f16* b_t = a_t + (size_t)CH * NROW;
  float* out = (float*)d_out;
  f16* wq = (f16*)d_out;
  f16* o16 = (f16*)d_out;
  f16* wq3 = (f16*)d_ws;
  f16* on_t = b_t;

  k_pass0<<<256, 256, 0, stream>>>(w_pa, w_ga, w_pb, w_gb, wq);
  k_pass1<<<4096, 256, 0, stream>>>(z, pm, ln_in_w, ln_in_b, wq, a_t, b_t);
  k_pass2<<<2048, 256, 0, stream>>>(a_t, b_t, o16);
  k_cvt2<<<128, 256, 0, stream>>>(w_g, w_o, wq3);
  k_pass3a<<<4096, 256, 0, stream>>>(o16, ln_out_w, ln_out_b, on_t);
  k_pass3b<<<4096, 256, 0, stream>>>(z, ln_in_w, ln_in_b, on_t, wq3, out);
}